// Round 6
// baseline (284.191 us; speedup 1.0000x reference)
//
#include <hip/hip_runtime.h>
#include <hip/hip_bf16.h>

#define S_LEN 2048
#define BATCH 4
#define NH 8
#define DK 16
#define DM 256
#define DP 128           // NH*DK
#define L2E 1.4426950408889634f

typedef short bf16x8 __attribute__((ext_vector_type(8)));
typedef short short4v __attribute__((ext_vector_type(4)));
typedef float f32x16 __attribute__((ext_vector_type(16)));

__device__ __forceinline__ short f2bf(float x) {
    __hip_bfloat16 h = __float2bfloat16(x);
    return __builtin_bit_cast(short, h);
}

// ---------------- Mask dtype detection ----------------
__global__ __launch_bounds__(256) void detect_mask_dtype(
    const unsigned int* __restrict__ m, int* __restrict__ flag)
{
    unsigned int u = m[blockIdx.x * 256 + threadIdx.x];  // first 1 MB only
    if (u & 0xFFFFFF00u) atomicOr(flag, 1);
}

// ---------------- Mask pack, pre-scrambled into MFMA D-fragment bit order --
__global__ __launch_bounds__(256) void pack_mask(
    const void* __restrict__ mraw, unsigned short* __restrict__ ms,
    const int* __restrict__ flag)
{
    const size_t i = (size_t)blockIdx.x * 256 + threadIdx.x;
    int v;
    if (*flag == 0) v = ((const int*)mraw)[i] != 0;
    else            v = ((const unsigned char*)mraw)[i] != 0;
    unsigned long long W = __ballot(v);
    const int c = threadIdx.x & 63;
    if (c < 4) {
        const int g2 = c >> 1, hi = c & 1;
        unsigned long long Wsh = W >> (32*g2 + 4*hi);
        unsigned int val = 0;
        #pragma unroll
        for (int r = 0; r < 16; ++r)
            val |= (unsigned int)((Wsh >> ((r & 3) + 8*(r >> 2))) & 1ull) << r;
        const size_t row = i >> 11;                        // b*S + q
        const size_t g = (((i & 2047) >> 5) & ~1ull) + g2; // global 32-key group
        ms[(row << 7) + (g << 1) + hi] = (unsigned short)val;
    }
}

// ---------------- V ones-rows init: rows 16 and 20 of each head = 1.0 ------
__global__ __launch_bounds__(256) void vinit(short* __restrict__ Vb)
{
    const int tid = blockIdx.x * 256 + threadIdx.x;       // 131072 total
    const int bh = tid >> 12;
    const int rem = tid & 4095;
    const int row = 16 + (rem >> 11) * 4;                 // 16 or 20
    const int s = rem & 2047;
    Vb[((size_t)bh * 32 + row) * S_LEN + s] = (short)0x3F80;  // bf16 1.0
}

// ---------------- Kernel 1: fused QKV projections (fp32 math, bf16 out) ----
// 8 rows/block (1024 blocks, 4/CU) + A/B software-pipelined W prefetch.
#define LOADW8(DST, K) do {                                                 \
    _Pragma("unroll")                                                       \
    for (int _kk = 0; _kk < 8; ++_kk) {                                     \
        DST##q[_kk] = Wq[((K) + _kk)*DP + c];                               \
        DST##k[_kk] = Wk[((K) + _kk)*DP + c];                               \
        DST##v[_kk] = Wv[((K) + _kk)*DP + c];                               \
    }                                                                       \
} while(0)

#define FMA4(SRC, OFF, K) do {                                              \
    _Pragma("unroll")                                                       \
    for (int _r = 0; _r < 4; ++_r) {                                        \
        float4 _x = *(const float4*)&xs[0][rh*4 + _r][(K)];                 \
        aq[_r] = fmaf(_x.x, SRC##q[OFF+0], fmaf(_x.y, SRC##q[OFF+1],        \
                 fmaf(_x.z, SRC##q[OFF+2], fmaf(_x.w, SRC##q[OFF+3], aq[_r])))); \
        float4 _y = *(const float4*)&xs[1][rh*4 + _r][(K)];                 \
        ak[_r] = fmaf(_y.x, SRC##k[OFF+0], fmaf(_y.y, SRC##k[OFF+1],        \
                 fmaf(_y.z, SRC##k[OFF+2], fmaf(_y.w, SRC##k[OFF+3], ak[_r])))); \
        float4 _z = *(const float4*)&xs[2][rh*4 + _r][(K)];                 \
        av[_r] = fmaf(_z.x, SRC##v[OFF+0], fmaf(_z.y, SRC##v[OFF+1],        \
                 fmaf(_z.z, SRC##v[OFF+2], fmaf(_z.w, SRC##v[OFF+3], av[_r])))); \
    }                                                                       \
} while(0)

__global__ __launch_bounds__(256) void proj_qkv(
    const float* __restrict__ Xq, const float* __restrict__ Xk, const float* __restrict__ Xv,
    const float* __restrict__ Wq, const float* __restrict__ Wk, const float* __restrict__ Wv,
    short* __restrict__ Qb, short* __restrict__ Kb, short* __restrict__ Vb)
{
    __shared__ float xs[3][8][DM];
    const int t = threadIdx.x;
    const int row0 = blockIdx.x * 8;

    #pragma unroll
    for (int i = 0; i < 6; ++i) {
        int idx = (i * 256 + t) * 4;
        int m = idx >> 11;
        int rem = idx & 2047;
        int r = rem >> 8;
        int k = rem & 255;
        const float* src = (m == 0) ? Xq : (m == 1) ? Xk : Xv;
        *(float4*)&xs[m][r][k] = *(const float4*)(src + (size_t)(row0 + r) * DM + k);
    }
    __syncthreads();

    const int c = t & 127;
    const int rh = t >> 7;
    float aq[4] = {0,0,0,0}, ak[4] = {0,0,0,0}, av[4] = {0,0,0,0};

    float Aq[8], Ak[8], Av[8], Bq[8], Bk[8], Bv[8];
    LOADW8(A, 0);
    #pragma unroll
    for (int k = 0; k < DM; k += 16) {
        LOADW8(B, k + 8);
        FMA4(A, 0, k); FMA4(A, 4, k + 4);
        if (k + 16 < DM) LOADW8(A, k + 16);
        FMA4(B, 0, k + 8); FMA4(B, 4, k + 12);
    }

    const int h = c >> 4, d = c & 15;
    #pragma unroll
    for (int r = 0; r < 4; ++r) {
        int row = row0 + rh*4 + r;
        int b = row >> 11, s = row & (S_LEN - 1);
        size_t o = (((size_t)(b * NH + h)) * S_LEN + s) * DK + d;
        Qb[o] = f2bf(aq[r] * (0.25f * L2E));   // fold 1/sqrt(dk) and log2(e)
        Kb[o] = f2bf(ak[r]);
    }
    {
        int row = row0 + rh*4;
        int b = row >> 11, sl = row & (S_LEN - 1);
        short4v vv = { f2bf(av[0]), f2bf(av[1]), f2bf(av[2]), f2bf(av[3]) };
        *(short4v*)(Vb + ((size_t)(b * NH + h) * 32 + d) * S_LEN + sl) = vv;
    }
}

// ---------------- Kernel 2: MFMA flash attention, 2-tile pipelined ---------
#define LOADTILE(MW, KF, VF, TILE) do {                                     \
    const int _k0 = (TILE) * 128;                                           \
    MW = *(const uint4*)(mrow + (TILE) * 4);                                \
    _Pragma("unroll")                                                       \
    for (int _kt = 0; _kt < 4; ++_kt) {                                     \
        const short* _kp = kbase + (size_t)(_k0 + _kt*32 + lq) * DK;        \
        KF[_kt].h2[0] = *(const short4v*)(_kp + 4*hi);                      \
        KF[_kt].h2[1] = *(const short4v*)(_kp + 8 + 4*hi);                  \
    }                                                                       \
    _Pragma("unroll")                                                       \
    for (int _j = 0; _j < 8; ++_j) {                                        \
        const short* _vp = vrow + _k0 + _j*16;                              \
        VF[_j].h2[0] = *(const short4v*)(_vp + 4*hi);                       \
        VF[_j].h2[1] = *(const short4v*)(_vp + 8 + 4*hi);                   \
    }                                                                       \
} while(0)

#define COMPTILE(MW, KF, VF) do {                                           \
    _Pragma("unroll")                                                       \
    for (int _kt = 0; _kt < 4; ++_kt) {                                     \
        const unsigned int _W =                                             \
            ((_kt==0)?MW.x:(_kt==1)?MW.y:(_kt==2)?MW.z:MW.w) >> hish;       \
        f32x16 _ci;                                                         \
        _Pragma("unroll")                                                   \
        for (int _r = 0; _r < 16; ++_r)                                     \
            _ci[_r] = __int_as_float(((int)(_W << (31 - _r)) >> 31) & 0xC2C80000); \
        f32x16 _p = __builtin_amdgcn_mfma_f32_32x32x16_bf16(KF[_kt].v, qf.v, _ci, 0, 0, 0); \
        _Pragma("unroll")                                                   \
        for (int _r = 0; _r < 16; ++_r) _p[_r] = __builtin_amdgcn_exp2f(_p[_r]); \
        _Pragma("unroll")                                                   \
        for (int _j = 0; _j < 2; ++_j) {                                    \
            union { bf16x8 v; short s[8]; } _pf;                            \
            _Pragma("unroll")                                               \
            for (int _e = 0; _e < 8; ++_e) _pf.s[_e] = f2bf(_p[_j*8 + _e]); \
            acc = __builtin_amdgcn_mfma_f32_32x32x16_bf16(VF[_kt*2 + _j].v, _pf.v, acc, 0, 0, 0); \
        }                                                                   \
    }                                                                       \
} while(0)

__global__ __launch_bounds__(256) void attn_mfma(
    const short* __restrict__ Qb, const short* __restrict__ Kb, const short* __restrict__ Vb,
    const unsigned int* __restrict__ ms, float* __restrict__ ctx_out)
{
    const int bh = blockIdx.y;
    const int b = bh >> 3, h = bh & 7;
    const int wave = threadIdx.x >> 6, lane = threadIdx.x & 63;
    const int lq = lane & 31, hi = lane >> 5;
    const int qrow = blockIdx.x * 128 + wave * 32 + lq;
    const int hish = hi * 16;

    union Frag { bf16x8 v; short4v h2[2]; };
    Frag qf;
    {
        const short* qp = Qb + ((size_t)bh * S_LEN + qrow) * DK;
        qf.h2[0] = *(const short4v*)(qp + 4*hi);
        qf.h2[1] = *(const short4v*)(qp + 8 + 4*hi);
    }

    f32x16 acc;
    #pragma unroll
    for (int i = 0; i < 16; ++i) acc[i] = 0.f;

    const short* kbase = Kb + (size_t)bh * S_LEN * DK;
    const short* vrow  = Vb + ((size_t)bh * 32 + lq) * S_LEN;
    const unsigned int* mrow = ms + ((size_t)b * S_LEN + qrow) * 64;

    uint4 mwA, mwB;
    Frag kfA[4], kfB[4], vfA[8], vfB[8];

    LOADTILE(mwA, kfA, vfA, 0);
    #pragma unroll
    for (int tile = 0; tile < S_LEN / 128; tile += 2) {
        LOADTILE(mwB, kfB, vfB, tile + 1);
        COMPTILE(mwA, kfA, vfA);
        if (tile + 2 < S_LEN / 128) LOADTILE(mwA, kfA, vfA, tile + 2);
        COMPTILE(mwB, kfB, vfB);
    }

    // epilogue: acc[8] = sum of P over all keys (ones-row of V); normalize
    const float invl = 1.0f / acc[8];
    float* cbase = ctx_out + ((size_t)b * S_LEN + qrow) * DP + h * DK;
    float4 o1 = { acc[0]*invl, acc[1]*invl, acc[2]*invl, acc[3]*invl };
    float4 o2 = { acc[4]*invl, acc[5]*invl, acc[6]*invl, acc[7]*invl };
    *(float4*)(cbase + 4*hi) = o1;
    *(float4*)(cbase + 8 + 4*hi) = o2;
}

// ---------------- Kernel 3: FC (ctx @ Wfc) + LayerNorm ----------------
__global__ __launch_bounds__(256) void fc_ln(
    const float* __restrict__ ctx, const float* __restrict__ Wfc,
    const float* __restrict__ gamma, const float* __restrict__ beta,
    float* __restrict__ out)
{
    __shared__ float cs[4][DP];
    __shared__ float ys[4][256];
    __shared__ float red[8];
    const int t = threadIdx.x;
    const int row0 = blockIdx.x * 4;

    {
        int idx = t * 2;
        int r = idx >> 7, k = idx & 127;
        *(float2*)&cs[r][k] = *(const float2*)(ctx + (size_t)(row0 + r) * DP + k);
    }
    __syncthreads();

    float acc[4] = {0,0,0,0};
    for (int k = 0; k < DP; k += 4) {
        const float w0 = Wfc[(k+0)*DM + t];
        const float w1 = Wfc[(k+1)*DM + t];
        const float w2 = Wfc[(k+2)*DM + t];
        const float w3 = Wfc[(k+3)*DM + t];
        #pragma unroll
        for (int r = 0; r < 4; ++r) {
            float4 x = *(const float4*)&cs[r][k];
            acc[r] = fmaf(x.x, w0, fmaf(x.y, w1, fmaf(x.z, w2, fmaf(x.w, w3, acc[r]))));
        }
    }

    #pragma unroll
    for (int r = 0; r < 4; ++r) ys[r][t] = acc[r];
    __syncthreads();

    const int w = t >> 6, lj = t & 63;
    {
        float a0 = ys[w][lj], a1 = ys[w][lj+64], a2 = ys[w][lj+128], a3 = ys[w][lj+192];
        float s1 = a0 + a1 + a2 + a3;
        float s2 = a0*a0 + a1*a1 + a2*a2 + a3*a3;
        #pragma unroll
        for (int off = 32; off; off >>= 1) {
            s1 += __shfl_xor(s1, off);
            s2 += __shfl_xor(s2, off);
        }
        if (lj == 0) {
            float mu = s1 * (1.0f/256.0f);
            float var = s2 * (1.0f/256.0f) - mu*mu;
            red[w*2]     = mu;
            red[w*2 + 1] = rsqrtf(var + 1e-5f);
        }
    }
    __syncthreads();

    const float g = gamma[t], be = beta[t];
    #pragma unroll
    for (int r = 0; r < 4; ++r) {
        float y = (acc[r] - red[r*2]) * red[r*2 + 1];
        out[(size_t)(row0 + r) * DM + t] = fmaf(y, g, be);
    }
}

extern "C" void kernel_launch(void* const* d_in, const int* in_sizes, int n_in,
                              void* d_out, int out_size, void* d_ws, size_t ws_size,
                              hipStream_t stream)
{
    const float* Xq = (const float*)d_in[0];
    const float* Xk = (const float*)d_in[1];
    const float* Xv = (const float*)d_in[2];
    const void* mask_raw = d_in[3];
    const float* Wq  = (const float*)d_in[4];
    const float* Wk  = (const float*)d_in[5];
    const float* Wv  = (const float*)d_in[6];
    const float* Wfc = (const float*)d_in[7];
    const float* gamma = (const float*)d_in[8];
    const float* beta  = (const float*)d_in[9];
    float* out = (float*)d_out;

    const size_t headsz = (size_t)BATCH * NH * S_LEN * DK;      // 1,048,576 elems
    const size_t maskelems = (size_t)BATCH * S_LEN * S_LEN;     // 16.8M

    short* Qb = (short*)d_ws;                 // 2MB bf16
    short* Kb = Qb + headsz;                  // 2MB
    short* Vb = Kb + headsz;                  // 4MB (padded transposed [bh][32][S])
    float* ctx = (float*)(Vb + 2 * headsz);   // 4MB f32 [B,S,128]
    unsigned short* msk = (unsigned short*)(ctx + (size_t)BATCH * S_LEN * DP);  // 2MB scrambled bitmask
    int* flag = (int*)(msk + maskelems / 16);

    hipMemsetAsync(flag, 0, sizeof(int), stream);
    detect_mask_dtype<<<dim3(1024), dim3(256), 0, stream>>>((const unsigned int*)mask_raw, flag);
    pack_mask<<<dim3(maskelems / 256), dim3(256), 0, stream>>>(mask_raw, msk, flag);
    vinit<<<dim3(512), dim3(256), 0, stream>>>(Vb);

    proj_qkv<<<dim3(BATCH * S_LEN / 8), dim3(256), 0, stream>>>(Xq, Xk, Xv, Wq, Wk, Wv, Qb, Kb, Vb);
    attn_mfma<<<dim3(S_LEN / 128, BATCH * NH), dim3(256), 0, stream>>>(Qb, Kb, Vb, (const unsigned int*)msk, ctx);
    fc_ln<<<dim3(BATCH * S_LEN / 4), dim3(256), 0, stream>>>(ctx, Wfc, gamma, beta, out);
}

// Round 7
// 164.079 us; speedup vs baseline: 1.7320x; 1.7320x over previous
//
#include <hip/hip_runtime.h>
#include <hip/hip_bf16.h>

#define S_LEN 2048
#define BATCH 4
#define NH 8
#define DK 16
#define DM 256
#define DP 128           // NH*DK
#define L2E 1.4426950408889634f

typedef short bf16x8 __attribute__((ext_vector_type(8)));
typedef short short4v __attribute__((ext_vector_type(4)));
typedef float f32x16 __attribute__((ext_vector_type(16)));

__device__ __forceinline__ short f2bf(float x) {
    __hip_bfloat16 h = __float2bfloat16(x);
    return __builtin_bit_cast(short, h);
}

union Frag { bf16x8 v; short4v h2[2]; };

// ---------------- Mask dtype detection ----------------
__global__ __launch_bounds__(256) void detect_mask_dtype(
    const unsigned int* __restrict__ m, int* __restrict__ flag)
{
    unsigned int u = m[blockIdx.x * 256 + threadIdx.x];  // first 1 MB only
    if (u & 0xFFFFFF00u) atomicOr(flag, 1);
}

// ---------------- Mask pack, pre-scrambled into MFMA D-fragment bit order --
__global__ __launch_bounds__(256) void pack_mask(
    const void* __restrict__ mraw, unsigned short* __restrict__ ms,
    const int* __restrict__ flag)
{
    const size_t i = (size_t)blockIdx.x * 256 + threadIdx.x;
    int v;
    if (*flag == 0) v = ((const int*)mraw)[i] != 0;
    else            v = ((const unsigned char*)mraw)[i] != 0;
    unsigned long long W = __ballot(v);
    const int c = threadIdx.x & 63;
    if (c < 4) {
        const int g2 = c >> 1, hi = c & 1;
        unsigned long long Wsh = W >> (32*g2 + 4*hi);
        unsigned int val = 0;
        #pragma unroll
        for (int r = 0; r < 16; ++r)
            val |= (unsigned int)((Wsh >> ((r & 3) + 8*(r >> 2))) & 1ull) << r;
        const size_t row = i >> 11;                        // b*S + q
        const size_t g = (((i & 2047) >> 5) & ~1ull) + g2; // global 32-key group
        ms[(row << 7) + (g << 1) + hi] = (unsigned short)val;
    }
}

// ---------------- V ones-rows init: rows 16 and 20 of each head = 1.0 ------
__global__ __launch_bounds__(256) void vinit(short* __restrict__ Vb)
{
    const int tid = blockIdx.x * 256 + threadIdx.x;       // 131072 total
    const int bh = tid >> 12;
    const int rem = tid & 4095;
    const int row = 16 + (rem >> 11) * 4;                 // 16 or 20
    const int s = rem & 2047;
    Vb[((size_t)bh * 32 + row) * S_LEN + s] = (short)0x3F80;  // bf16 1.0
}

// ---------------- X -> bf16 (concatenated [3][8192][256]) ------------------
__global__ __launch_bounds__(256) void cvt_x(
    const float* __restrict__ Xq, const float* __restrict__ Xk,
    const float* __restrict__ Xv, short* __restrict__ Xb)
{
    const int tid = blockIdx.x * 256 + threadIdx.x;       // 786432
    const int m = tid >> 18;
    const int local = tid & 262143;
    const float* src = (m == 0) ? Xq : (m == 1) ? Xk : Xv;
    const float4 a = *(const float4*)(src + (size_t)local * 8);
    const float4 b = *(const float4*)(src + (size_t)local * 8 + 4);
    bf16x8 o = { f2bf(a.x), f2bf(a.y), f2bf(a.z), f2bf(a.w),
                 f2bf(b.x), f2bf(b.y), f2bf(b.z), f2bf(b.w) };
    *(bf16x8*)(Xb + (size_t)m * 2097152 + (size_t)local * 8) = o;
}

// ---------------- W -> bf16 transposed [3][128][256]; Q gets scale ---------
__global__ __launch_bounds__(256) void cvt_w(
    const float* __restrict__ Wq, const float* __restrict__ Wk,
    const float* __restrict__ Wv, short* __restrict__ Wt)
{
    const int tid = blockIdx.x * 256 + threadIdx.x;       // 98304
    const int m = tid >> 15;
    const int rem = tid & 32767;
    const int k = rem >> 7, c = rem & 127;
    const float* W = (m == 0) ? Wq : (m == 1) ? Wk : Wv;
    const float scale = (m == 0) ? 0.25f * L2E : 1.0f;    // fold 1/sqrt(dk)*log2(e) into Wq
    Wt[((size_t)m * 128 + c) * 256 + k] = f2bf(W[(size_t)k * 128 + c] * scale);
}

// ---------------- Kernel 1: QKV projection via MFMA ----------------
// grid (256, 3); block 256 = 4 waves; wave w computes rows s0..s0+31 x cols 32w..32w+31
__global__ __launch_bounds__(256) void proj_mfma(
    const short* __restrict__ Xb, const short* __restrict__ Wt,
    short* __restrict__ Qb, short* __restrict__ Kb, short* __restrict__ Vb)
{
    const int inp = blockIdx.y;                 // 0=Q,1=K,2=V
    const int s0 = blockIdx.x * 32;
    const int wave = threadIdx.x >> 6, lane = threadIdx.x & 63;
    const int lq = lane & 31, hi = lane >> 5;
    const int c = wave * 32 + lq;               // out col 0..127

    const short* xrow = Xb + (size_t)inp * 2097152 + (size_t)(s0 + lq) * 256;
    const short* wrow = Wt + ((size_t)inp * 128 + c) * 256;

    f32x16 acc;
    #pragma unroll
    for (int i = 0; i < 16; ++i) acc[i] = 0.f;

    #pragma unroll
    for (int kb = 0; kb < 16; ++kb) {
        Frag af, bf_;
        af.h2[0]  = *(const short4v*)(xrow + kb*16 + 4*hi);
        af.h2[1]  = *(const short4v*)(xrow + kb*16 + 8 + 4*hi);
        bf_.h2[0] = *(const short4v*)(wrow + kb*16 + 4*hi);
        bf_.h2[1] = *(const short4v*)(wrow + kb*16 + 8 + 4*hi);
        acc = __builtin_amdgcn_mfma_f32_32x32x16_bf16(af.v, bf_.v, acc, 0, 0, 0);
    }

    // D: col(lane&31)=c, row(reg r)=s0 + (r&3)+8*(r>>2)+4*hi
    const int b = s0 >> 11, sl = s0 & (S_LEN - 1);
    const int h = c >> 4, d = c & 15;
    if (inp < 2) {
        short* dst = (inp == 0) ? Qb : Kb;
        #pragma unroll
        for (int r = 0; r < 16; ++r) {
            const int s = sl + (r & 3) + 8*(r >> 2) + 4*hi;
            dst[(((size_t)(b * NH + h)) * S_LEN + s) * DK + d] = f2bf(acc[r]);
        }
    } else {
        short* vb = Vb + (((size_t)(b * NH + h)) * 32 + d) * S_LEN + sl;
        #pragma unroll
        for (int g = 0; g < 4; ++g) {
            short4v vv = { f2bf(acc[4*g]), f2bf(acc[4*g+1]), f2bf(acc[4*g+2]), f2bf(acc[4*g+3]) };
            *(short4v*)(vb + 8*g + 4*hi) = vv;
        }
    }
}

// ---------------- Kernel 2: MFMA flash attention, split-K ----------------
// grid (S/128, B*H, ns); block 256 = 4 waves x 32 q-rows. r5 structure (32 VGPR).
__global__ __launch_bounds__(256, 8) void attn_mfma(
    const short* __restrict__ Qb, const short* __restrict__ Kb, const short* __restrict__ Vb,
    const unsigned int* __restrict__ ms, float* __restrict__ pacc, float* __restrict__ pl)
{
    const int bh = blockIdx.y;
    const int b = bh >> 3;
    const int z = blockIdx.z;
    const int wave = threadIdx.x >> 6, lane = threadIdx.x & 63;
    const int lq = lane & 31, hi = lane >> 5;
    const int qrow = blockIdx.x * 128 + wave * 32 + lq;
    const int hish = hi * 16;

    Frag qf;
    {
        const short* qp = Qb + ((size_t)bh * S_LEN + qrow) * DK;
        qf.h2[0] = *(const short4v*)(qp + 4*hi);
        qf.h2[1] = *(const short4v*)(qp + 8 + 4*hi);
    }

    f32x16 acc;
    #pragma unroll
    for (int i = 0; i < 16; ++i) acc[i] = 0.f;

    const short* kbase = Kb + (size_t)bh * S_LEN * DK;
    const short* vrow  = Vb + ((size_t)bh * 32 + lq) * S_LEN;
    const unsigned int* mrow = ms + ((size_t)b * S_LEN + qrow) * 64;

    const int tiles = (S_LEN / 128) / gridDim.z;
    const int t0 = z * tiles, t1 = t0 + tiles;

    for (int tile = t0; tile < t1; ++tile) {
        const int k0 = tile * 128;
        const uint4 mw = *(const uint4*)(mrow + tile * 4);   // 4 x 32-key groups

        #pragma unroll
        for (int kt = 0; kt < 4; ++kt) {
            // mask -> C-init: -100 where masked (bit order matches D layout)
            const unsigned int W = ((kt==0)?mw.x:(kt==1)?mw.y:(kt==2)?mw.z:mw.w) >> hish;
            f32x16 ci;
            #pragma unroll
            for (int r = 0; r < 16; ++r)
                ci[r] = __int_as_float(((int)(W << (31 - r)) >> 31) & 0xC2C80000);

            // QK^T for 32 keys (log2-domain scores via scaled Wq)
            Frag kf;
            const short* kp = kbase + (size_t)(k0 + kt*32 + lq) * DK;
            kf.h2[0] = *(const short4v*)(kp + 4*hi);
            kf.h2[1] = *(const short4v*)(kp + 8 + 4*hi);
            f32x16 p = __builtin_amdgcn_mfma_f32_32x32x16_bf16(kf.v, qf.v, ci, 0, 0, 0);

            #pragma unroll
            for (int r = 0; r < 16; ++r) p[r] = __builtin_amdgcn_exp2f(p[r]);

            // PV: 2 MFMAs of 16 keys; P^T regs feed B-frag directly
            #pragma unroll
            for (int j = 0; j < 2; ++j) {
                union { bf16x8 v; short s[8]; } pf;
                #pragma unroll
                for (int e = 0; e < 8; ++e) pf.s[e] = f2bf(p[j*8 + e]);
                Frag vf;
                const short* vp = vrow + k0 + (kt*2 + j) * 16;
                vf.h2[0] = *(const short4v*)(vp + 4*hi);
                vf.h2[1] = *(const short4v*)(vp + 8 + 4*hi);
                acc = __builtin_amdgcn_mfma_f32_32x32x16_bf16(vf.v, pf.v, acc, 0, 0, 0);
            }
        }
    }

    // partial store (unnormalized); acc[8] = sum of P (ones-row of V)
    float* pb = pacc + (((size_t)z * (BATCH*NH) + bh) * S_LEN + qrow) * 16;
    float4 o1 = { acc[0], acc[1], acc[2], acc[3] };
    float4 o2 = { acc[4], acc[5], acc[6], acc[7] };
    *(float4*)(pb + 4*hi) = o1;
    *(float4*)(pb + 8 + 4*hi) = o2;
    if (hi == 0) pl[((size_t)z * (BATCH*NH) + bh) * S_LEN + qrow] = acc[8];
}

// ---------------- Kernel 2b: combine split-K partials -> ctx [B,S,128] -----
__global__ __launch_bounds__(256) void attn_combine(
    const float* __restrict__ pacc, const float* __restrict__ pl,
    float* __restrict__ ctx, int ns)
{
    const int tid = blockIdx.x * 256 + threadIdx.x;   // 262144 total
    const int d4 = (tid & 3) * 4;
    const int q  = (tid >> 2) & (S_LEN - 1);
    const int bh = tid >> 13;
    const int b = bh >> 3, h = bh & 7;

    float4 s = {0.f, 0.f, 0.f, 0.f};
    float L = 0.f;
    for (int z = 0; z < ns; ++z) {
        const size_t o = ((size_t)z * (BATCH*NH) + bh) * S_LEN + q;
        float4 a = *(const float4*)(pacc + o * 16 + d4);
        s.x += a.x; s.y += a.y; s.z += a.z; s.w += a.w;
        L += pl[o];
    }
    const float inv = 1.0f / L;
    float4 o = { s.x * inv, s.y * inv, s.z * inv, s.w * inv };
    *(float4*)(ctx + ((size_t)b * S_LEN + q) * DP + h * DK + d4) = o;
}

// ---------------- Kernel 3: FC (ctx @ Wfc) + LayerNorm ----------------
__global__ __launch_bounds__(256) void fc_ln(
    const float* __restrict__ ctx, const float* __restrict__ Wfc,
    const float* __restrict__ gamma, const float* __restrict__ beta,
    float* __restrict__ out)
{
    __shared__ float cs[4][DP];
    __shared__ float ys[4][256];
    __shared__ float red[8];
    const int t = threadIdx.x;
    const int row0 = blockIdx.x * 4;

    {
        int idx = t * 2;
        int r = idx >> 7, k = idx & 127;
        *(float2*)&cs[r][k] = *(const float2*)(ctx + (size_t)(row0 + r) * DP + k);
    }
    __syncthreads();

    float acc[4] = {0,0,0,0};
    for (int k = 0; k < DP; k += 4) {
        const float w0 = Wfc[(k+0)*DM + t];
        const float w1 = Wfc[(k+1)*DM + t];
        const float w2 = Wfc[(k+2)*DM + t];
        const float w3 = Wfc[(k+3)*DM + t];
        #pragma unroll
        for (int r = 0; r < 4; ++r) {
            float4 x = *(const float4*)&cs[r][k];
            acc[r] = fmaf(x.x, w0, fmaf(x.y, w1, fmaf(x.z, w2, fmaf(x.w, w3, acc[r]))));
        }
    }

    #pragma unroll
    for (int r = 0; r < 4; ++r) ys[r][t] = acc[r];
    __syncthreads();

    const int w = t >> 6, lj = t & 63;
    {
        float a0 = ys[w][lj], a1 = ys[w][lj+64], a2 = ys[w][lj+128], a3 = ys[w][lj+192];
        float s1 = a0 + a1 + a2 + a3;
        float s2 = a0*a0 + a1*a1 + a2*a2 + a3*a3;
        #pragma unroll
        for (int off = 32; off; off >>= 1) {
            s1 += __shfl_xor(s1, off);
            s2 += __shfl_xor(s2, off);
        }
        if (lj == 0) {
            float mu = s1 * (1.0f/256.0f);
            float var = s2 * (1.0f/256.0f) - mu*mu;
            red[w*2]     = mu;
            red[w*2 + 1] = rsqrtf(var + 1e-5f);
        }
    }
    __syncthreads();

    const float g = gamma[t], be = beta[t];
    #pragma unroll
    for (int r = 0; r < 4; ++r) {
        float y = (acc[r] - red[r*2]) * red[r*2 + 1];
        out[(size_t)(row0 + r) * DM + t] = fmaf(y, g, be);
    }
}

extern "C" void kernel_launch(void* const* d_in, const int* in_sizes, int n_in,
                              void* d_out, int out_size, void* d_ws, size_t ws_size,
                              hipStream_t stream)
{
    const float* Xq = (const float*)d_in[0];
    const float* Xk = (const float*)d_in[1];
    const float* Xv = (const float*)d_in[2];
    const void* mask_raw = d_in[3];
    const float* Wq  = (const float*)d_in[4];
    const float* Wk  = (const float*)d_in[5];
    const float* Wv  = (const float*)d_in[6];
    const float* Wfc = (const float*)d_in[7];
    const float* gamma = (const float*)d_in[8];
    const float* beta  = (const float*)d_in[9];
    float* out = (float*)d_out;

    const size_t headsz = (size_t)BATCH * NH * S_LEN * DK;      // 1,048,576 elems
    const size_t maskelems = (size_t)BATCH * S_LEN * S_LEN;     // 16.8M

    char* wsb = (char*)d_ws;
    short* Qb = (short*)wsb;                              // 2 MB
    short* Kb = Qb + headsz;                              // 2 MB
    short* Vb = Kb + headsz;                              // 4 MB ([bh][32][S])
    float* ctx = (float*)(Vb + 2 * headsz);               // 4 MB
    unsigned short* msk = (unsigned short*)(ctx + (size_t)BATCH * S_LEN * DP);  // 2 MB
    char* R = (char*)(msk + maskelems / 16);              // overlap region

    // phase A (pre-attn): Xb [3][8192][256] bf16, Wt [3][128][256] bf16, flag
    short* Xb = (short*)R;                                // 12 MB
    short* Wt = Xb + (size_t)3 * 2097152;                 // 192 KB
    int* flag = (int*)(Wt + 3 * 128 * 256);
    // phase B (attn+): pacc/pl alias the same region
    float* pacc = (float*)R;
    const size_t fixed_bytes = (size_t)(R - wsb);
    const size_t phaseA_bytes = (size_t)3*2097152*2 + 98304*2 + 4;
    size_t ns = 4;
    while (ns > 1 && fixed_bytes + (ns * ((size_t)BATCH*NH*S_LEN*17*4) > phaseA_bytes
                                    ? ns * ((size_t)BATCH*NH*S_LEN*17*4) : phaseA_bytes) > ws_size)
        ns >>= 1;
    float* pl = pacc + ns * (size_t)BATCH * NH * S_LEN * 16;

    hipMemsetAsync(flag, 0, sizeof(int), stream);
    detect_mask_dtype<<<dim3(1024), dim3(256), 0, stream>>>((const unsigned int*)mask_raw, flag);
    pack_mask<<<dim3(maskelems / 256), dim3(256), 0, stream>>>(mask_raw, msk, flag);
    cvt_x<<<dim3(3072), dim3(256), 0, stream>>>(Xq, Xk, Xv, Xb);
    cvt_w<<<dim3(384), dim3(256), 0, stream>>>(Wq, Wk, Wv, Wt);
    vinit<<<dim3(512), dim3(256), 0, stream>>>(Vb);

    proj_mfma<<<dim3(BATCH * S_LEN / 32, 3), dim3(256), 0, stream>>>(Xb, Wt, Qb, Kb, Vb);
    attn_mfma<<<dim3(S_LEN / 128, BATCH * NH, (unsigned)ns), dim3(256), 0, stream>>>(
        Qb, Kb, Vb, (const unsigned int*)msk, pacc, pl);
    attn_combine<<<dim3(BATCH * NH * S_LEN * 4 / 256), dim3(256), 0, stream>>>(pacc, pl, ctx, (int)ns);
    fc_ln<<<dim3(BATCH * S_LEN / 4), dim3(256), 0, stream>>>(ctx, Wfc, gamma, beta, out);
}

// Round 8
// 113.450 us; speedup vs baseline: 2.5050x; 1.4463x over previous
//
#include <hip/hip_runtime.h>
#include <hip/hip_bf16.h>

#define S_LEN 2048
#define BATCH 4
#define NH 8
#define DK 16
#define DM 256
#define DP 128           // NH*DK
#define L2E 1.4426950408889634f

typedef short bf16x8 __attribute__((ext_vector_type(8)));
typedef short short4v __attribute__((ext_vector_type(4)));
typedef float f32x16 __attribute__((ext_vector_type(16)));

__device__ __forceinline__ short f2bf(float x) {
    __hip_bfloat16 h = __float2bfloat16(x);
    return __builtin_bit_cast(short, h);
}

union Frag { bf16x8 v; short4v h2[2]; };

// ---------------- Mask dtype detection ----------------
__global__ __launch_bounds__(256) void detect_mask_dtype(
    const unsigned int* __restrict__ m, int* __restrict__ flag)
{
    unsigned int u = m[blockIdx.x * 256 + threadIdx.x];  // first 1 MB only
    if (u & 0xFFFFFF00u) atomicOr(flag, 1);
}

// ---------------- Mask pack: scrambled to MFMA D-frag order, tile-major ----
// u16 at [tile][row][w][hi] : bit r = mask[row][tile*128 + w*32 + 4*hi + (r&3)+8*(r>>2)]
__global__ __launch_bounds__(256) void pack_mask(
    const void* __restrict__ mraw, unsigned short* __restrict__ ms,
    const int* __restrict__ flag)
{
    const size_t i = (size_t)blockIdx.x * 256 + threadIdx.x;
    int v;
    if (*flag == 0) v = ((const int*)mraw)[i] != 0;
    else            v = ((const unsigned char*)mraw)[i] != 0;
    unsigned long long W = __ballot(v);
    const int c = threadIdx.x & 63;
    if (c < 4) {
        const int g2 = c >> 1, hi = c & 1;
        unsigned long long Wsh = W >> (32*g2 + 4*hi);
        unsigned int val = 0;
        #pragma unroll
        for (int r = 0; r < 16; ++r)
            val |= (unsigned int)((Wsh >> ((r & 3) + 8*(r >> 2))) & 1ull) << r;
        const size_t row = i >> 11;                            // b*S + q
        const int g = (int)(((i & 2047) >> 5) & ~1u) + g2;     // 32-key group 0..63
        const int tile = g >> 2, w = g & 3;
        ms[(size_t)tile * (BATCH*S_LEN*8) + row*8 + w*2 + hi] = (unsigned short)val;
    }
}

// ---------------- V ones-rows init: rows 16 and 20 of each head = 1.0 ------
__global__ __launch_bounds__(256) void vinit(short* __restrict__ Vb)
{
    const int tid = blockIdx.x * 256 + threadIdx.x;       // 131072 total
    const int bh = tid >> 12;
    const int rem = tid & 4095;
    const int row = 16 + (rem >> 11) * 4;                 // 16 or 20
    const int s = rem & 2047;
    Vb[((size_t)bh * 32 + row) * S_LEN + s] = (short)0x3F80;  // bf16 1.0
}

// ---------------- X -> bf16 (concatenated [3][8192][256]) ------------------
__global__ __launch_bounds__(256) void cvt_x(
    const float* __restrict__ Xq, const float* __restrict__ Xk,
    const float* __restrict__ Xv, short* __restrict__ Xb)
{
    const int tid = blockIdx.x * 256 + threadIdx.x;       // 786432
    const int m = tid >> 18;
    const int local = tid & 262143;
    const float* src = (m == 0) ? Xq : (m == 1) ? Xk : Xv;
    const float4 a = *(const float4*)(src + (size_t)local * 8);
    const float4 b = *(const float4*)(src + (size_t)local * 8 + 4);
    bf16x8 o = { f2bf(a.x), f2bf(a.y), f2bf(a.z), f2bf(a.w),
                 f2bf(b.x), f2bf(b.y), f2bf(b.z), f2bf(b.w) };
    *(bf16x8*)(Xb + (size_t)m * 2097152 + (size_t)local * 8) = o;
}

// ---------------- W -> bf16 transposed [3][128][256]; Q gets scale ---------
__global__ __launch_bounds__(256) void cvt_w(
    const float* __restrict__ Wq, const float* __restrict__ Wk,
    const float* __restrict__ Wv, short* __restrict__ Wt)
{
    const int tid = blockIdx.x * 256 + threadIdx.x;       // 98304
    const int m = tid >> 15;
    const int rem = tid & 32767;
    const int k = rem >> 7, c = rem & 127;
    const float* W = (m == 0) ? Wq : (m == 1) ? Wk : Wv;
    const float scale = (m == 0) ? 0.25f * L2E : 1.0f;    // fold 1/sqrt(dk)*log2(e) into Wq
    Wt[((size_t)m * 128 + c) * 256 + k] = f2bf(W[(size_t)k * 128 + c] * scale);
}

// ---------------- Kernel 1: QKV projection via MFMA (X staged in LDS) ------
// grid (256, 3); block 256 = 4 waves; wave w: rows s0..s0+31 x cols 32w..32w+31
__global__ __launch_bounds__(256) void proj_mfma(
    const short* __restrict__ Xb, const short* __restrict__ Wt,
    short* __restrict__ Qb, short* __restrict__ Kb, short* __restrict__ Vb)
{
    __shared__ short xs_s[32 * 260];            // pitch 260 shorts (130 dw = 2-way free)
    const int inp = blockIdx.y;                 // 0=Q,1=K,2=V
    const int s0 = blockIdx.x * 32;
    const int t = threadIdx.x;

    {
        const short* xsrc = Xb + (size_t)inp * 2097152 + (size_t)(s0 + (t >> 3)) * 256 + (t & 7) * 32;
        short* xdst = &xs_s[(t >> 3) * 260 + (t & 7) * 32];
        #pragma unroll
        for (int u = 0; u < 4; ++u) {
            uint4 xv = *(const uint4*)(xsrc + u * 8);
            *(uint2*)(xdst + u * 8)     = *(uint2*)&xv;
            *(uint2*)(xdst + u * 8 + 4) = *((uint2*)&xv + 1);
        }
    }
    __syncthreads();

    const int wave = t >> 6, lane = t & 63;
    const int lq = lane & 31, hi = lane >> 5;
    const int c = wave * 32 + lq;               // out col 0..127

    const short* wrow = Wt + ((size_t)inp * 128 + c) * 256;

    f32x16 acc;
    #pragma unroll
    for (int i = 0; i < 16; ++i) acc[i] = 0.f;

    #pragma unroll
    for (int kb = 0; kb < 16; ++kb) {
        Frag af, bf_;
        af.h2[0]  = *(const short4v*)&xs_s[lq * 260 + kb*16 + 4*hi];
        af.h2[1]  = *(const short4v*)&xs_s[lq * 260 + kb*16 + 8 + 4*hi];
        bf_.h2[0] = *(const short4v*)(wrow + kb*16 + 4*hi);
        bf_.h2[1] = *(const short4v*)(wrow + kb*16 + 8 + 4*hi);
        acc = __builtin_amdgcn_mfma_f32_32x32x16_bf16(af.v, bf_.v, acc, 0, 0, 0);
    }

    // D: col(lane&31)=c, row(reg r)=s0 + (r&3)+8*(r>>2)+4*hi
    const int b = s0 >> 11, sl = s0 & (S_LEN - 1);
    const int h = c >> 4, d = c & 15;
    if (inp < 2) {
        short* dst = (inp == 0) ? Qb : Kb;
        #pragma unroll
        for (int r = 0; r < 16; ++r) {
            const int s = sl + (r & 3) + 8*(r >> 2) + 4*hi;
            dst[(((size_t)(b * NH + h)) * S_LEN + s) * DK + d] = f2bf(acc[r]);
        }
    } else {
        short* vb = Vb + (((size_t)(b * NH + h)) * 32 + d) * S_LEN + sl;
        #pragma unroll
        for (int g = 0; g < 4; ++g) {
            short4v vv = { f2bf(acc[4*g]), f2bf(acc[4*g+1]), f2bf(acc[4*g+2]), f2bf(acc[4*g+3]) };
            *(short4v*)(vb + 8*g + 4*hi) = vv;
        }
    }
}

// ---------------- Kernel 2: MFMA flash attention, LDS-staged K/V -----------
// grid (S/128, B*H, ns); block 256 = 4 waves x 32 q-rows.
__global__ __launch_bounds__(256, 8) void attn_mfma(
    const short* __restrict__ Qb, const short* __restrict__ Kb, const short* __restrict__ Vb,
    const unsigned int* __restrict__ ms, float* __restrict__ pacc, float* __restrict__ pl)
{
    __shared__ short kt_s[128 * 20];   // K tile: pitch 20 shorts (10 dw)
    __shared__ short vt_s[32 * 132];   // V^T tile: pitch 132 shorts (66 dw)

    const int bh = blockIdx.y;
    const int b = bh >> 3;
    const int z = blockIdx.z;
    const int t = threadIdx.x;
    const int wave = t >> 6, lane = t & 63;
    const int lq = lane & 31, hi = lane >> 5;
    const int qrow = blockIdx.x * 128 + wave * 32 + lq;
    const int hish = hi * 16;

    Frag qf;
    {
        const short* qp = Qb + ((size_t)bh * S_LEN + qrow) * DK;
        qf.h2[0] = *(const short4v*)(qp + 4*hi);
        qf.h2[1] = *(const short4v*)(qp + 8 + 4*hi);
    }

    f32x16 acc;
    #pragma unroll
    for (int i = 0; i < 16; ++i) acc[i] = 0.f;

    const short* kbase = Kb + (size_t)bh * S_LEN * DK;
    const short* vbase = Vb + (size_t)bh * 32 * S_LEN;
    const unsigned int* mbase = ms + ((size_t)b * S_LEN + qrow) * 4;

    const int tiles = (S_LEN / 128) / gridDim.z;
    const int t0 = z * tiles, t1 = t0 + tiles;

    for (int tile = t0; tile < t1; ++tile) {
        const int k0 = tile * 128;

        // ---- stage K tile (4KB, contiguous) and V^T tile (8KB, 256B rows)
        {
            const uint4 kv = *(const uint4*)(kbase + (size_t)k0 * DK + t * 8);
            short* kdst = &kt_s[(t >> 1) * 20 + (t & 1) * 8];
            *(uint2*)(kdst)     = *(uint2*)&kv;
            *(uint2*)(kdst + 4) = *((uint2*)&kv + 1);

            const short* vsrc = vbase + (size_t)(t >> 3) * S_LEN + k0 + (t & 7) * 16;
            uint4 v0 = *(const uint4*)(vsrc);
            uint4 v1 = *(const uint4*)(vsrc + 8);
            short* vdst = &vt_s[(t >> 3) * 132 + (t & 7) * 16];
            *(uint2*)(vdst)      = *(uint2*)&v0;
            *(uint2*)(vdst + 4)  = *((uint2*)&v0 + 1);
            *(uint2*)(vdst + 8)  = *(uint2*)&v1;
            *(uint2*)(vdst + 12) = *((uint2*)&v1 + 1);
        }
        __syncthreads();

        const uint4 mw = *(const uint4*)(mbase + (size_t)tile * (BATCH * S_LEN * 4));

        #pragma unroll
        for (int kt = 0; kt < 4; ++kt) {
            // mask -> C-init: -100 where masked (bit order matches D layout)
            const unsigned int W = ((kt==0)?mw.x:(kt==1)?mw.y:(kt==2)?mw.z:mw.w) >> hish;
            f32x16 ci;
            #pragma unroll
            for (int r = 0; r < 16; ++r)
                ci[r] = __int_as_float(((int)(W << (31 - r)) >> 31) & 0xC2C80000);

            // QK^T for 32 keys (log2-domain scores via scaled Wq)
            Frag kf;
            kf.h2[0] = *(const short4v*)&kt_s[(kt*32 + lq) * 20 + 4*hi];
            kf.h2[1] = *(const short4v*)&kt_s[(kt*32 + lq) * 20 + 8 + 4*hi];
            f32x16 p = __builtin_amdgcn_mfma_f32_32x32x16_bf16(kf.v, qf.v, ci, 0, 0, 0);

            #pragma unroll
            for (int r = 0; r < 16; ++r) p[r] = __builtin_amdgcn_exp2f(p[r]);

            // PV: 2 MFMAs of 16 keys; P^T regs feed B-frag directly
            #pragma unroll
            for (int j = 0; j < 2; ++j) {
                union { bf16x8 v; short s[8]; } pf;
                #pragma unroll
                for (int e = 0; e < 8; ++e) pf.s[e] = f2bf(p[j*8 + e]);
                Frag vf;
                const int vo = lq * 132 + (kt*2 + j) * 16 + 4*hi;
                vf.h2[0] = *(const short4v*)&vt_s[vo];
                vf.h2[1] = *(const short4v*)&vt_s[vo + 8];
                acc = __builtin_amdgcn_mfma_f32_32x32x16_bf16(vf.v, pf.v, acc, 0, 0, 0);
            }
        }
        __syncthreads();   // protect LDS before next tile's stage
    }

    // partial store (unnormalized); acc[8] = sum of P (ones-row of V)
    float* pb = pacc + (((size_t)z * (BATCH*NH) + bh) * S_LEN + qrow) * 16;
    float4 o1 = { acc[0], acc[1], acc[2], acc[3] };
    float4 o2 = { acc[4], acc[5], acc[6], acc[7] };
    *(float4*)(pb + 4*hi) = o1;
    *(float4*)(pb + 8 + 4*hi) = o2;
    if (hi == 0) pl[((size_t)z * (BATCH*NH) + bh) * S_LEN + qrow] = acc[8];
}

// ---------------- Kernel 2b: combine split-K partials -> ctx [B,S,128] -----
__global__ __launch_bounds__(256) void attn_combine(
    const float* __restrict__ pacc, const float* __restrict__ pl,
    float* __restrict__ ctx, int ns)
{
    const int tid = blockIdx.x * 256 + threadIdx.x;   // 262144 total
    const int d4 = (tid & 3) * 4;
    const int q  = (tid >> 2) & (S_LEN - 1);
    const int bh = tid >> 13;
    const int b = bh >> 3, h = bh & 7;

    float4 s = {0.f, 0.f, 0.f, 0.f};
    float L = 0.f;
    for (int z = 0; z < ns; ++z) {
        const size_t o = ((size_t)z * (BATCH*NH) + bh) * S_LEN + q;
        float4 a = *(const float4*)(pacc + o * 16 + d4);
        s.x += a.x; s.y += a.y; s.z += a.z; s.w += a.w;
        L += pl[o];
    }
    const float inv = 1.0f / L;
    float4 o = { s.x * inv, s.y * inv, s.z * inv, s.w * inv };
    *(float4*)(ctx + ((size_t)b * S_LEN + q) * DP + h * DK + d4) = o;
}

// ---------------- Kernel 3: FC (ctx @ Wfc) + LayerNorm ----------------
__global__ __launch_bounds__(256) void fc_ln(
    const float* __restrict__ ctx, const float* __restrict__ Wfc,
    const float* __restrict__ gamma, const float* __restrict__ beta,
    float* __restrict__ out)
{
    __shared__ float cs[4][DP];
    __shared__ float ys[4][256];
    __shared__ float red[8];
    const int t = threadIdx.x;
    const int row0 = blockIdx.x * 4;

    {
        int idx = t * 2;
        int r = idx >> 7, k = idx & 127;
        *(float2*)&cs[r][k] = *(const float2*)(ctx + (size_t)(row0 + r) * DP + k);
    }
    __syncthreads();

    float acc[4] = {0,0,0,0};
    for (int k = 0; k < DP; k += 4) {
        const float w0 = Wfc[(k+0)*DM + t];
        const float w1 = Wfc[(k+1)*DM + t];
        const float w2 = Wfc[(k+2)*DM + t];
        const float w3 = Wfc[(k+3)*DM + t];
        #pragma unroll
        for (int r = 0; r < 4; ++r) {
            float4 x = *(const float4*)&cs[r][k];
            acc[r] = fmaf(x.x, w0, fmaf(x.y, w1, fmaf(x.z, w2, fmaf(x.w, w3, acc[r]))));
        }
    }

    #pragma unroll
    for (int r = 0; r < 4; ++r) ys[r][t] = acc[r];
    __syncthreads();

    const int w = t >> 6, lj = t & 63;
    {
        float a0 = ys[w][lj], a1 = ys[w][lj+64], a2 = ys[w][lj+128], a3 = ys[w][lj+192];
        float s1 = a0 + a1 + a2 + a3;
        float s2 = a0*a0 + a1*a1 + a2*a2 + a3*a3;
        #pragma unroll
        for (int off = 32; off; off >>= 1) {
            s1 += __shfl_xor(s1, off);
            s2 += __shfl_xor(s2, off);
        }
        if (lj == 0) {
            float mu = s1 * (1.0f/256.0f);
            float var = s2 * (1.0f/256.0f) - mu*mu;
            red[w*2]     = mu;
            red[w*2 + 1] = rsqrtf(var + 1e-5f);
        }
    }
    __syncthreads();

    const float g = gamma[t], be = beta[t];
    #pragma unroll
    for (int r = 0; r < 4; ++r) {
        float y = (acc[r] - red[r*2]) * red[r*2 + 1];
        out[(size_t)(row0 + r) * DM + t] = fmaf(y, g, be);
    }
}

extern "C" void kernel_launch(void* const* d_in, const int* in_sizes, int n_in,
                              void* d_out, int out_size, void* d_ws, size_t ws_size,
                              hipStream_t stream)
{
    const float* Xq = (const float*)d_in[0];
    const float* Xk = (const float*)d_in[1];
    const float* Xv = (const float*)d_in[2];
    const void* mask_raw = d_in[3];
    const float* Wq  = (const float*)d_in[4];
    const float* Wk  = (const float*)d_in[5];
    const float* Wv  = (const float*)d_in[6];
    const float* Wfc = (const float*)d_in[7];
    const float* gamma = (const float*)d_in[8];
    const float* beta  = (const float*)d_in[9];
    float* out = (float*)d_out;

    const size_t headsz = (size_t)BATCH * NH * S_LEN * DK;      // 1,048,576 elems
    const size_t maskelems = (size_t)BATCH * S_LEN * S_LEN;     // 16.8M

    char* wsb = (char*)d_ws;
    short* Qb = (short*)wsb;                              // 2 MB
    short* Kb = Qb + headsz;                              // 2 MB
    short* Vb = Kb + headsz;                              // 4 MB ([bh][32][S])
    float* ctx = (float*)(Vb + 2 * headsz);               // 4 MB
    unsigned short* msk = (unsigned short*)(ctx + (size_t)BATCH * S_LEN * DP);  // 2 MB
    char* R = (char*)(msk + maskelems / 16);              // overlap region

    // phase A (pre-attn): Xb [3][8192][256] bf16, Wt [3][128][256] bf16, flag
    short* Xb = (short*)R;                                // 12 MB
    short* Wt = Xb + (size_t)3 * 2097152;                 // 192 KB
    int* flag = (int*)(Wt + 3 * 128 * 256);
    // phase B (attn+): pacc/pl alias the same region
    float* pacc = (float*)R;
    const size_t fixed_bytes = (size_t)(R - wsb);
    const size_t phaseA_bytes = (size_t)3*2097152*2 + 98304*2 + 4;
    size_t ns = 4;
    while (ns > 1 && fixed_bytes + (ns * ((size_t)BATCH*NH*S_LEN*17*4) > phaseA_bytes
                                    ? ns * ((size_t)BATCH*NH*S_LEN*17*4) : phaseA_bytes) > ws_size)
        ns >>= 1;
    float* pl = pacc + ns * (size_t)BATCH * NH * S_LEN * 16;

    hipMemsetAsync(flag, 0, sizeof(int), stream);
    detect_mask_dtype<<<dim3(1024), dim3(256), 0, stream>>>((const unsigned int*)mask_raw, flag);
    pack_mask<<<dim3(maskelems / 256), dim3(256), 0, stream>>>(mask_raw, msk, flag);
    cvt_x<<<dim3(3072), dim3(256), 0, stream>>>(Xq, Xk, Xv, Xb);
    cvt_w<<<dim3(384), dim3(256), 0, stream>>>(Wq, Wk, Wv, Wt);
    vinit<<<dim3(512), dim3(256), 0, stream>>>(Vb);

    proj_mfma<<<dim3(BATCH * S_LEN / 32, 3), dim3(256), 0, stream>>>(Xb, Wt, Qb, Kb, Vb);
    attn_mfma<<<dim3(S_LEN / 128, BATCH * NH, (unsigned)ns), dim3(256), 0, stream>>>(
        Qb, Kb, Vb, (const unsigned int*)msk, pacc, pl);
    attn_combine<<<dim3(BATCH * NH * S_LEN * 4 / 256), dim3(256), 0, stream>>>(pacc, pl, ctx, (int)ns);
    fc_ln<<<dim3(BATCH * S_LEN / 4), dim3(256), 0, stream>>>(ctx, Wfc, gamma, beta, out);
}

// Round 9
// 107.005 us; speedup vs baseline: 2.6559x; 1.0602x over previous
//
#include <hip/hip_runtime.h>
#include <hip/hip_bf16.h>

#define S_LEN 2048
#define BATCH 4
#define NH 8
#define DK 16
#define DM 256
#define DP 128           // NH*DK
#define L2E 1.4426950408889634f

typedef short bf16x8 __attribute__((ext_vector_type(8)));
typedef short short4v __attribute__((ext_vector_type(4)));
typedef float f32x16 __attribute__((ext_vector_type(16)));

__device__ __forceinline__ short f2bf(float x) {
    __hip_bfloat16 h = __float2bfloat16(x);
    return __builtin_bit_cast(short, h);
}

union Frag { bf16x8 v; short4v h2[2]; };

// ---------------- Mask dtype detection ----------------
__global__ __launch_bounds__(256) void detect_mask_dtype(
    const unsigned int* __restrict__ m, int* __restrict__ flag)
{
    unsigned int u = m[blockIdx.x * 256 + threadIdx.x];  // first 1 MB only
    if (u & 0xFFFFFF00u) atomicOr(flag, 1);
}

// ---------------- Mask pack: scrambled to MFMA D-frag order, tile-major ----
// Double-ballot bit permutation; one u64 store per wave (4 consecutive u16s).
// u16 at [tile][row][w][hi] : bit r = mask[row][tile*128 + w*32 + 4*hi + (r&3)+8*(r>>2)]
__global__ __launch_bounds__(256) void pack_mask(
    const void* __restrict__ mraw, unsigned long long* __restrict__ ms64,
    const int* __restrict__ flag)
{
    const size_t i = (size_t)blockIdx.x * 256 + threadIdx.x;
    int v;
    if (*flag == 0) v = ((const int*)mraw)[i] != 0;
    else            v = ((const unsigned char*)mraw)[i] != 0;
    const unsigned long long W = __ballot(v);

    const int lane = threadIdx.x & 63;
    const int src = 32*((lane>>5)&1) + 4*((lane>>4)&1) + 8*((lane>>2)&3) + (lane&3);
    const unsigned long long W2 = __ballot((int)((W >> src) & 1ull));

    if (lane == 0) {
        const size_t row = i >> 11;            // b*S + q
        const int koff = (int)(i & 2047);      // 64-aligned key offset
        const int tile = koff >> 7;
        const int w0h  = (koff >> 6) & 1;
        ms64[(size_t)tile * (BATCH*S_LEN*2) + row*2 + w0h] = W2;
    }
}

// ---------------- V ones-rows init: rows 16 and 20 of each head = 1.0 ------
__global__ __launch_bounds__(256) void vinit(short* __restrict__ Vb)
{
    const int tid = blockIdx.x * 256 + threadIdx.x;       // 131072 total
    const int bh = tid >> 12;
    const int rem = tid & 4095;
    const int row = 16 + (rem >> 11) * 4;                 // 16 or 20
    const int s = rem & 2047;
    Vb[((size_t)bh * 32 + row) * S_LEN + s] = (short)0x3F80;  // bf16 1.0
}

// ---------------- W -> bf16 transposed [3][128][256]; Q gets scale ---------
__global__ __launch_bounds__(256) void cvt_w(
    const float* __restrict__ Wq, const float* __restrict__ Wk,
    const float* __restrict__ Wv, short* __restrict__ Wt)
{
    const int tid = blockIdx.x * 256 + threadIdx.x;       // 98304
    const int m = tid >> 15;
    const int rem = tid & 32767;
    const int k = rem >> 7, c = rem & 127;
    const float* W = (m == 0) ? Wq : (m == 1) ? Wk : Wv;
    const float scale = (m == 0) ? 0.25f * L2E : 1.0f;    // fold 1/sqrt(dk)*log2(e) into Wq
    Wt[((size_t)m * 128 + c) * 256 + k] = f2bf(W[(size_t)k * 128 + c] * scale);
}

// ---------------- Kernel 1: QKV projection via MFMA (f32 X staged+cvt) -----
// grid (256, 3); block 256 = 4 waves; wave w: rows s0..s0+31 x cols 32w..32w+31
__global__ __launch_bounds__(256) void proj_mfma(
    const float* __restrict__ Xq, const float* __restrict__ Xk, const float* __restrict__ Xv,
    const short* __restrict__ Wt,
    short* __restrict__ Qb, short* __restrict__ Kb, short* __restrict__ Vb)
{
    __shared__ short xs_s[32 * 260];            // pitch 260 shorts (130 dw = 2-way free)
    const int inp = blockIdx.y;                 // 0=Q,1=K,2=V
    const int s0 = blockIdx.x * 32;
    const int t = threadIdx.x;

    {
        const float* xsrc = ((inp == 0) ? Xq : (inp == 1) ? Xk : Xv)
                          + (size_t)(s0 + (t >> 3)) * 256 + (t & 7) * 32;
        short* xdst = &xs_s[(t >> 3) * 260 + (t & 7) * 32];
        #pragma unroll
        for (int u = 0; u < 8; ++u) {
            float4 xv = *(const float4*)(xsrc + u * 4);
            short4v o = { f2bf(xv.x), f2bf(xv.y), f2bf(xv.z), f2bf(xv.w) };
            *(short4v*)(xdst + u * 4) = o;
        }
    }
    __syncthreads();

    const int wave = t >> 6, lane = t & 63;
    const int lq = lane & 31, hi = lane >> 5;
    const int c = wave * 32 + lq;               // out col 0..127

    const short* wrow = Wt + ((size_t)inp * 128 + c) * 256;

    f32x16 acc;
    #pragma unroll
    for (int i = 0; i < 16; ++i) acc[i] = 0.f;

    #pragma unroll
    for (int kb = 0; kb < 16; ++kb) {
        Frag af, bf_;
        af.h2[0]  = *(const short4v*)&xs_s[lq * 260 + kb*16 + 4*hi];
        af.h2[1]  = *(const short4v*)&xs_s[lq * 260 + kb*16 + 8 + 4*hi];
        bf_.h2[0] = *(const short4v*)(wrow + kb*16 + 4*hi);
        bf_.h2[1] = *(const short4v*)(wrow + kb*16 + 8 + 4*hi);
        acc = __builtin_amdgcn_mfma_f32_32x32x16_bf16(af.v, bf_.v, acc, 0, 0, 0);
    }

    // D: col(lane&31)=c, row(reg r)=s0 + (r&3)+8*(r>>2)+4*hi
    const int b = s0 >> 11, sl = s0 & (S_LEN - 1);
    const int h = c >> 4, d = c & 15;
    if (inp < 2) {
        short* dst = (inp == 0) ? Qb : Kb;
        #pragma unroll
        for (int r = 0; r < 16; ++r) {
            const int s = sl + (r & 3) + 8*(r >> 2) + 4*hi;
            dst[(((size_t)(b * NH + h)) * S_LEN + s) * DK + d] = f2bf(acc[r]);
        }
    } else {
        short* vb = Vb + (((size_t)(b * NH + h)) * 32 + d) * S_LEN + sl;
        #pragma unroll
        for (int g = 0; g < 4; ++g) {
            short4v vv = { f2bf(acc[4*g]), f2bf(acc[4*g+1]), f2bf(acc[4*g+2]), f2bf(acc[4*g+3]) };
            *(short4v*)(vb + 8*g + 4*hi) = vv;
        }
    }
}

// ---------------- Kernel 2: MFMA flash attention, LDS-staged K/V -----------
// grid (S/128, B*H, ns); block 256 = 4 waves x 32 q-rows.
__global__ __launch_bounds__(256, 8) void attn_mfma(
    const short* __restrict__ Qb, const short* __restrict__ Kb, const short* __restrict__ Vb,
    const unsigned int* __restrict__ ms, float* __restrict__ pacc, float* __restrict__ pl)
{
    __shared__ short kt_s[128 * 20];   // K tile: pitch 20 shorts (10 dw)
    __shared__ short vt_s[32 * 132];   // V^T tile: pitch 132 shorts (66 dw)

    const int bh = blockIdx.y;
    const int b = bh >> 3;
    const int z = blockIdx.z;
    const int t = threadIdx.x;
    const int wave = t >> 6, lane = t & 63;
    const int lq = lane & 31, hi = lane >> 5;
    const int qrow = blockIdx.x * 128 + wave * 32 + lq;
    const int hish = hi * 16;

    Frag qf;
    {
        const short* qp = Qb + ((size_t)bh * S_LEN + qrow) * DK;
        qf.h2[0] = *(const short4v*)(qp + 4*hi);
        qf.h2[1] = *(const short4v*)(qp + 8 + 4*hi);
    }

    f32x16 acc;
    #pragma unroll
    for (int i = 0; i < 16; ++i) acc[i] = 0.f;

    const short* kbase = Kb + (size_t)bh * S_LEN * DK;
    const short* vbase = Vb + (size_t)bh * 32 * S_LEN;
    const unsigned int* mbase = ms + ((size_t)b * S_LEN + qrow) * 4;

    const int tiles = (S_LEN / 128) / gridDim.z;
    const int t0 = z * tiles, t1 = t0 + tiles;

    for (int tile = t0; tile < t1; ++tile) {
        const int k0 = tile * 128;

        // ---- stage K tile (4KB, contiguous) and V^T tile (8KB, 256B rows)
        {
            const uint4 kv = *(const uint4*)(kbase + (size_t)k0 * DK + t * 8);
            short* kdst = &kt_s[(t >> 1) * 20 + (t & 1) * 8];
            *(uint2*)(kdst)     = *(uint2*)&kv;
            *(uint2*)(kdst + 4) = *((uint2*)&kv + 1);

            const short* vsrc = vbase + (size_t)(t >> 3) * S_LEN + k0 + (t & 7) * 16;
            uint4 v0 = *(const uint4*)(vsrc);
            uint4 v1 = *(const uint4*)(vsrc + 8);
            short* vdst = &vt_s[(t >> 3) * 132 + (t & 7) * 16];
            *(uint2*)(vdst)      = *(uint2*)&v0;
            *(uint2*)(vdst + 4)  = *((uint2*)&v0 + 1);
            *(uint2*)(vdst + 8)  = *(uint2*)&v1;
            *(uint2*)(vdst + 12) = *((uint2*)&v1 + 1);
        }
        __syncthreads();

        const uint4 mw = *(const uint4*)(mbase + (size_t)tile * (BATCH * S_LEN * 4));

        #pragma unroll
        for (int kt = 0; kt < 4; ++kt) {
            // mask -> C-init: -100 where masked (bit order matches D layout)
            const unsigned int W = ((kt==0)?mw.x:(kt==1)?mw.y:(kt==2)?mw.z:mw.w) >> hish;
            f32x16 ci;
            #pragma unroll
            for (int r = 0; r < 16; ++r)
                ci[r] = __int_as_float(((int)(W << (31 - r)) >> 31) & 0xC2C80000);

            // QK^T for 32 keys (log2-domain scores via scaled Wq)
            Frag kf;
            kf.h2[0] = *(const short4v*)&kt_s[(kt*32 + lq) * 20 + 4*hi];
            kf.h2[1] = *(const short4v*)&kt_s[(kt*32 + lq) * 20 + 8 + 4*hi];
            f32x16 p = __builtin_amdgcn_mfma_f32_32x32x16_bf16(kf.v, qf.v, ci, 0, 0, 0);

            #pragma unroll
            for (int r = 0; r < 16; ++r) p[r] = __builtin_amdgcn_exp2f(p[r]);

            // PV: 2 MFMAs of 16 keys; P^T regs feed B-frag directly
            #pragma unroll
            for (int j = 0; j < 2; ++j) {
                union { bf16x8 v; short s[8]; } pf;
                #pragma unroll
                for (int e = 0; e < 8; ++e) pf.s[e] = f2bf(p[j*8 + e]);
                Frag vf;
                const int vo = lq * 132 + (kt*2 + j) * 16 + 4*hi;
                vf.h2[0] = *(const short4v*)&vt_s[vo];
                vf.h2[1] = *(const short4v*)&vt_s[vo + 8];
                acc = __builtin_amdgcn_mfma_f32_32x32x16_bf16(vf.v, pf.v, acc, 0, 0, 0);
            }
        }
        __syncthreads();   // protect LDS before next tile's stage
    }

    // partial store (unnormalized); acc[8] = sum of P (ones-row of V)
    float* pb = pacc + (((size_t)z * (BATCH*NH) + bh) * S_LEN + qrow) * 16;
    float4 o1 = { acc[0], acc[1], acc[2], acc[3] };
    float4 o2 = { acc[4], acc[5], acc[6], acc[7] };
    *(float4*)(pb + 4*hi) = o1;
    *(float4*)(pb + 8 + 4*hi) = o2;
    if (hi == 0) pl[((size_t)z * (BATCH*NH) + bh) * S_LEN + qrow] = acc[8];
}

// ---------------- Kernel 3: combine + FC (ctx @ Wfc) + LayerNorm -----------
// 4 rows per block; combine of split-K partials happens while staging cs.
__global__ __launch_bounds__(256) void fc_ln(
    const float* __restrict__ pacc, const float* __restrict__ pl, int ns,
    const float* __restrict__ Wfc,
    const float* __restrict__ gamma, const float* __restrict__ beta,
    float* __restrict__ out)
{
    __shared__ float cs[4][DP];
    __shared__ float ys[4][256];
    __shared__ float red[8];
    const int t = threadIdx.x;
    const int row0 = blockIdx.x * 4;

    {
        const int idx = t * 2;
        const int r = idx >> 7, k = idx & 127;
        const int grow = row0 + r;
        const int b = grow >> 11, q = grow & (S_LEN - 1);
        const int h = k >> 4, d0 = k & 15;
        float sx = 0.f, sy = 0.f, L = 0.f;
        for (int z = 0; z < ns; ++z) {
            const size_t o = ((size_t)z * (BATCH*NH) + b * NH + h) * S_LEN + q;
            const float2 a = *(const float2*)(pacc + o * 16 + d0);
            sx += a.x; sy += a.y; L += pl[o];
        }
        const float inv = 1.0f / L;
        cs[r][k]     = sx * inv;
        cs[r][k + 1] = sy * inv;
    }
    __syncthreads();

    float acc[4] = {0,0,0,0};
    for (int k = 0; k < DP; k += 4) {
        const float w0 = Wfc[(k+0)*DM + t];
        const float w1 = Wfc[(k+1)*DM + t];
        const float w2 = Wfc[(k+2)*DM + t];
        const float w3 = Wfc[(k+3)*DM + t];
        #pragma unroll
        for (int r = 0; r < 4; ++r) {
            float4 x = *(const float4*)&cs[r][k];
            acc[r] = fmaf(x.x, w0, fmaf(x.y, w1, fmaf(x.z, w2, fmaf(x.w, w3, acc[r]))));
        }
    }

    #pragma unroll
    for (int r = 0; r < 4; ++r) ys[r][t] = acc[r];
    __syncthreads();

    const int w = t >> 6, lj = t & 63;
    {
        float a0 = ys[w][lj], a1 = ys[w][lj+64], a2 = ys[w][lj+128], a3 = ys[w][lj+192];
        float s1 = a0 + a1 + a2 + a3;
        float s2 = a0*a0 + a1*a1 + a2*a2 + a3*a3;
        #pragma unroll
        for (int off = 32; off; off >>= 1) {
            s1 += __shfl_xor(s1, off);
            s2 += __shfl_xor(s2, off);
        }
        if (lj == 0) {
            float mu = s1 * (1.0f/256.0f);
            float var = s2 * (1.0f/256.0f) - mu*mu;
            red[w*2]     = mu;
            red[w*2 + 1] = rsqrtf(var + 1e-5f);
        }
    }
    __syncthreads();

    const float g = gamma[t], be = beta[t];
    #pragma unroll
    for (int r = 0; r < 4; ++r) {
        float y = (acc[r] - red[r*2]) * red[r*2 + 1];
        out[(size_t)(row0 + r) * DM + t] = fmaf(y, g, be);
    }
}

extern "C" void kernel_launch(void* const* d_in, const int* in_sizes, int n_in,
                              void* d_out, int out_size, void* d_ws, size_t ws_size,
                              hipStream_t stream)
{
    const float* Xq = (const float*)d_in[0];
    const float* Xk = (const float*)d_in[1];
    const float* Xv = (const float*)d_in[2];
    const void* mask_raw = d_in[3];
    const float* Wq  = (const float*)d_in[4];
    const float* Wk  = (const float*)d_in[5];
    const float* Wv  = (const float*)d_in[6];
    const float* Wfc = (const float*)d_in[7];
    const float* gamma = (const float*)d_in[8];
    const float* beta  = (const float*)d_in[9];
    float* out = (float*)d_out;

    const size_t headsz = (size_t)BATCH * NH * S_LEN * DK;      // 1,048,576 elems
    const size_t maskelems = (size_t)BATCH * S_LEN * S_LEN;     // 16.8M

    char* wsb = (char*)d_ws;
    short* Qb = (short*)wsb;                              // 2 MB
    short* Kb = Qb + headsz;                              // 2 MB
    short* Vb = Kb + headsz;                              // 4 MB ([bh][32][S])
    unsigned short* msk = (unsigned short*)(Vb + 2 * headsz);   // 2 MB scrambled bitmask
    char* R = (char*)(msk + maskelems / 16);              // overlap region

    // phase A (proj): Wt [3][128][256] bf16 + flag
    short* Wt = (short*)R;                                // 192 KB
    int* flag = (int*)(Wt + 3 * 128 * 256);
    const size_t phaseA_bytes = (size_t)3*128*256*2 + 4;
    // phase B (attn+): pacc/pl alias the same region
    float* pacc = (float*)R;
    const size_t fixed_bytes = (size_t)(R - wsb);
    size_t ns = 4;
    while (ns > 1) {
        size_t phaseB = ns * ((size_t)BATCH*NH*S_LEN*17*4);
        size_t need = fixed_bytes + (phaseB > phaseA_bytes ? phaseB : phaseA_bytes);
        if (need <= ws_size) break;
        ns >>= 1;
    }
    float* pl = pacc + ns * (size_t)BATCH * NH * S_LEN * 16;

    hipMemsetAsync(flag, 0, sizeof(int), stream);
    detect_mask_dtype<<<dim3(1024), dim3(256), 0, stream>>>((const unsigned int*)mask_raw, flag);
    pack_mask<<<dim3(maskelems / 256), dim3(256), 0, stream>>>(
        mask_raw, (unsigned long long*)msk, flag);
    cvt_w<<<dim3(384), dim3(256), 0, stream>>>(Wq, Wk, Wv, Wt);
    vinit<<<dim3(512), dim3(256), 0, stream>>>(Vb);

    proj_mfma<<<dim3(BATCH * S_LEN / 32, 3), dim3(256), 0, stream>>>(Xq, Xk, Xv, Wt, Qb, Kb, Vb);
    attn_mfma<<<dim3(S_LEN / 128, BATCH * NH, (unsigned)ns), dim3(256), 0, stream>>>(
        Qb, Kb, Vb, (const unsigned int*)msk, pacc, pl);
    fc_ln<<<dim3(BATCH * S_LEN / 4), dim3(256), 0, stream>>>(pacc, pl, (int)ns, Wfc, gamma, beta, out);
}

// Round 10
// 94.186 us; speedup vs baseline: 3.0173x; 1.1361x over previous
//
#include <hip/hip_runtime.h>
#include <hip/hip_bf16.h>

#define S_LEN 2048
#define BATCH 4
#define NH 8
#define DK 16
#define DM 256
#define DP 128           // NH*DK
#define L2E 1.4426950408889634f

typedef short bf16x8 __attribute__((ext_vector_type(8)));
typedef short short4v __attribute__((ext_vector_type(4)));
typedef float f32x16 __attribute__((ext_vector_type(16)));

__device__ __forceinline__ short f2bf(float x) {
    __hip_bfloat16 h = __float2bfloat16(x);
    return __builtin_bit_cast(short, h);
}

union Frag { bf16x8 v; short4v h2[2]; };

// ---------------- Mask dtype detection ----------------
__global__ __launch_bounds__(256) void detect_mask_dtype(
    const unsigned int* __restrict__ m, int* __restrict__ flag)
{
    unsigned int u = m[blockIdx.x * 256 + threadIdx.x];  // first 1 MB only
    if (u & 0xFFFFFF00u) atomicOr(flag, 1);
}

// ---------------- Mask pack: scrambled to MFMA D-frag order, tile-major ----
// Each wave covers 256 keys: 4 independent coalesced loads (MLP), then per
// 64-key group: ballot -> permute-ballot -> one u64 store from lane 0.
// u64 layout: [tile][row][w0h]; bit j = mask key 64*w0h' + 32*(j>>5) +
// 4*((j>>4)&1) + 8*((j>>2)&3) + (j&3)  (matches MFMA D-frag C-init order)
__global__ __launch_bounds__(256) void pack_mask(
    const void* __restrict__ mraw, unsigned long long* __restrict__ ms64,
    const int* __restrict__ flag)
{
    const int lane = threadIdx.x & 63;
    const size_t kbase = ((size_t)blockIdx.x * 4 + (threadIdx.x >> 6)) * 256;
    const int isInt = (*flag == 0);

    int v[4];
    if (isInt) {
        const int* p = (const int*)mraw + kbase + lane;
        #pragma unroll
        for (int g = 0; g < 4; ++g) v[g] = p[g * 64];
    } else {
        const unsigned char* p = (const unsigned char*)mraw + kbase + lane;
        #pragma unroll
        for (int g = 0; g < 4; ++g) v[g] = p[g * 64];
    }

    const int src = 32*((lane>>5)&1) + 4*((lane>>4)&1) + 8*((lane>>2)&3) + (lane&3);
    const size_t row = kbase >> 11;            // b*S + q
    const int koff0 = (int)(kbase & 2047);

    #pragma unroll
    for (int g = 0; g < 4; ++g) {
        const unsigned long long W = __ballot(v[g] != 0);
        const unsigned long long W2 = __ballot((int)((W >> src) & 1ull));
        if (lane == 0) {
            const int koff = koff0 + g * 64;
            ms64[(size_t)(koff >> 7) * (BATCH*S_LEN*2) + row*2 + ((koff >> 6) & 1)] = W2;
        }
    }
}

// ---------------- V ones-rows init (+ flag zero; runs before detect) -------
__global__ __launch_bounds__(256) void vinit(short* __restrict__ Vb, int* __restrict__ flag)
{
    if (blockIdx.x == 0 && threadIdx.x == 0) *flag = 0;
    const int tid = blockIdx.x * 256 + threadIdx.x;       // 131072 total
    const int bh = tid >> 12;
    const int rem = tid & 4095;
    const int row = 16 + (rem >> 11) * 4;                 // 16 or 20
    const int s = rem & 2047;
    Vb[((size_t)bh * 32 + row) * S_LEN + s] = (short)0x3F80;  // bf16 1.0
}

// ---------------- W -> bf16 transposed [3][128][256]; Q gets scale ---------
__global__ __launch_bounds__(256) void cvt_w(
    const float* __restrict__ Wq, const float* __restrict__ Wk,
    const float* __restrict__ Wv, short* __restrict__ Wt)
{
    const int tid = blockIdx.x * 256 + threadIdx.x;       // 98304
    const int m = tid >> 15;
    const int rem = tid & 32767;
    const int k = rem >> 7, c = rem & 127;
    const float* W = (m == 0) ? Wq : (m == 1) ? Wk : Wv;
    const float scale = (m == 0) ? 0.25f * L2E : 1.0f;    // fold 1/sqrt(dk)*log2(e) into Wq
    Wt[((size_t)m * 128 + c) * 256 + k] = f2bf(W[(size_t)k * 128 + c] * scale);
}

// ---------------- Kernel 1: QKV projection via MFMA (f32 X staged+cvt) -----
// grid (256, 3); block 256 = 4 waves; wave w: rows s0..s0+31 x cols 32w..32w+31
__global__ __launch_bounds__(256) void proj_mfma(
    const float* __restrict__ Xq, const float* __restrict__ Xk, const float* __restrict__ Xv,
    const short* __restrict__ Wt,
    short* __restrict__ Qb, short* __restrict__ Kb, short* __restrict__ Vb)
{
    __shared__ short xs_s[32 * 260];            // pitch 260 shorts (130 dw = 2-way free)
    const int inp = blockIdx.y;                 // 0=Q,1=K,2=V
    const int s0 = blockIdx.x * 32;
    const int t = threadIdx.x;

    {
        const float* xsrc = ((inp == 0) ? Xq : (inp == 1) ? Xk : Xv)
                          + (size_t)(s0 + (t >> 3)) * 256 + (t & 7) * 32;
        short* xdst = &xs_s[(t >> 3) * 260 + (t & 7) * 32];
        #pragma unroll
        for (int u = 0; u < 8; ++u) {
            float4 xv = *(const float4*)(xsrc + u * 4);
            short4v o = { f2bf(xv.x), f2bf(xv.y), f2bf(xv.z), f2bf(xv.w) };
            *(short4v*)(xdst + u * 4) = o;
        }
    }
    __syncthreads();

    const int wave = t >> 6, lane = t & 63;
    const int lq = lane & 31, hi = lane >> 5;
    const int c = wave * 32 + lq;               // out col 0..127

    const short* wrow = Wt + ((size_t)inp * 128 + c) * 256;

    f32x16 acc;
    #pragma unroll
    for (int i = 0; i < 16; ++i) acc[i] = 0.f;

    #pragma unroll
    for (int kb = 0; kb < 16; ++kb) {
        Frag af, bf_;
        af.h2[0]  = *(const short4v*)&xs_s[lq * 260 + kb*16 + 4*hi];
        af.h2[1]  = *(const short4v*)&xs_s[lq * 260 + kb*16 + 8 + 4*hi];
        bf_.h2[0] = *(const short4v*)(wrow + kb*16 + 4*hi);
        bf_.h2[1] = *(const short4v*)(wrow + kb*16 + 8 + 4*hi);
        acc = __builtin_amdgcn_mfma_f32_32x32x16_bf16(af.v, bf_.v, acc, 0, 0, 0);
    }

    // D: col(lane&31)=c, row(reg r)=s0 + (r&3)+8*(r>>2)+4*hi
    const int b = s0 >> 11, sl = s0 & (S_LEN - 1);
    const int h = c >> 4, d = c & 15;
    if (inp < 2) {
        short* dst = (inp == 0) ? Qb : Kb;
        #pragma unroll
        for (int r = 0; r < 16; ++r) {
            const int s = sl + (r & 3) + 8*(r >> 2) + 4*hi;
            dst[(((size_t)(b * NH + h)) * S_LEN + s) * DK + d] = f2bf(acc[r]);
        }
    } else {
        short* vb = Vb + (((size_t)(b * NH + h)) * 32 + d) * S_LEN + sl;
        #pragma unroll
        for (int g = 0; g < 4; ++g) {
            short4v vv = { f2bf(acc[4*g]), f2bf(acc[4*g+1]), f2bf(acc[4*g+2]), f2bf(acc[4*g+3]) };
            *(short4v*)(vb + 8*g + 4*hi) = vv;
        }
    }
}

// ---------------- Kernel 2: MFMA flash attention, LDS-staged K/V -----------
// grid (S/128, B*H, ns); block 256 = 4 waves x 32 q-rows.
__global__ __launch_bounds__(256, 8) void attn_mfma(
    const short* __restrict__ Qb, const short* __restrict__ Kb, const short* __restrict__ Vb,
    const unsigned int* __restrict__ ms, float* __restrict__ pacc, float* __restrict__ pl)
{
    __shared__ short kt_s[128 * 20];   // K tile: pitch 20 shorts (10 dw)
    __shared__ short vt_s[32 * 132];   // V^T tile: pitch 132 shorts (66 dw)

    const int bh = blockIdx.y;
    const int b = bh >> 3;
    const int z = blockIdx.z;
    const int t = threadIdx.x;
    const int wave = t >> 6, lane = t & 63;
    const int lq = lane & 31, hi = lane >> 5;
    const int qrow = blockIdx.x * 128 + wave * 32 + lq;
    const int hish = hi * 16;

    Frag qf;
    {
        const short* qp = Qb + ((size_t)bh * S_LEN + qrow) * DK;
        qf.h2[0] = *(const short4v*)(qp + 4*hi);
        qf.h2[1] = *(const short4v*)(qp + 8 + 4*hi);
    }

    f32x16 acc;
    #pragma unroll
    for (int i = 0; i < 16; ++i) acc[i] = 0.f;

    const short* kbase = Kb + (size_t)bh * S_LEN * DK;
    const short* vbase = Vb + (size_t)bh * 32 * S_LEN;
    const unsigned int* mbase = ms + ((size_t)b * S_LEN + qrow) * 4;

    const int tiles = (S_LEN / 128) / gridDim.z;
    const int t0 = z * tiles, t1 = t0 + tiles;

    for (int tile = t0; tile < t1; ++tile) {
        const int k0 = tile * 128;

        // ---- stage K tile (4KB, contiguous) and V^T tile (8KB, 256B rows)
        {
            const uint4 kv = *(const uint4*)(kbase + (size_t)k0 * DK + t * 8);
            short* kdst = &kt_s[(t >> 1) * 20 + (t & 1) * 8];
            *(uint2*)(kdst)     = *(uint2*)&kv;
            *(uint2*)(kdst + 4) = *((uint2*)&kv + 1);

            const short* vsrc = vbase + (size_t)(t >> 3) * S_LEN + k0 + (t & 7) * 16;
            uint4 v0 = *(const uint4*)(vsrc);
            uint4 v1 = *(const uint4*)(vsrc + 8);
            short* vdst = &vt_s[(t >> 3) * 132 + (t & 7) * 16];
            *(uint2*)(vdst)      = *(uint2*)&v0;
            *(uint2*)(vdst + 4)  = *((uint2*)&v0 + 1);
            *(uint2*)(vdst + 8)  = *(uint2*)&v1;
            *(uint2*)(vdst + 12) = *((uint2*)&v1 + 1);
        }
        __syncthreads();

        const uint4 mw = *(const uint4*)(mbase + (size_t)tile * (BATCH * S_LEN * 4));

        #pragma unroll
        for (int kt = 0; kt < 4; ++kt) {
            // mask -> C-init: -100 where masked (bit order matches D layout)
            const unsigned int W = ((kt==0)?mw.x:(kt==1)?mw.y:(kt==2)?mw.z:mw.w) >> hish;
            f32x16 ci;
            #pragma unroll
            for (int r = 0; r < 16; ++r)
                ci[r] = __int_as_float(((int)(W << (31 - r)) >> 31) & 0xC2C80000);

            // QK^T for 32 keys (log2-domain scores via scaled Wq)
            Frag kf;
            kf.h2[0] = *(const short4v*)&kt_s[(kt*32 + lq) * 20 + 4*hi];
            kf.h2[1] = *(const short4v*)&kt_s[(kt*32 + lq) * 20 + 8 + 4*hi];
            f32x16 p = __builtin_amdgcn_mfma_f32_32x32x16_bf16(kf.v, qf.v, ci, 0, 0, 0);

            #pragma unroll
            for (int r = 0; r < 16; ++r) p[r] = __builtin_amdgcn_exp2f(p[r]);

            // PV: 2 MFMAs of 16 keys; P^T regs feed B-frag directly
            #pragma unroll
            for (int j = 0; j < 2; ++j) {
                union { bf16x8 v; short s[8]; } pf;
                #pragma unroll
                for (int e = 0; e < 8; ++e) pf.s[e] = f2bf(p[j*8 + e]);
                Frag vf;
                const int vo = lq * 132 + (kt*2 + j) * 16 + 4*hi;
                vf.h2[0] = *(const short4v*)&vt_s[vo];
                vf.h2[1] = *(const short4v*)&vt_s[vo + 8];
                acc = __builtin_amdgcn_mfma_f32_32x32x16_bf16(vf.v, pf.v, acc, 0, 0, 0);
            }
        }
        __syncthreads();   // protect LDS before next tile's stage
    }

    // partial store (unnormalized); acc[8] = sum of P (ones-row of V)
    float* pb = pacc + (((size_t)z * (BATCH*NH) + bh) * S_LEN + qrow) * 16;
    float4 o1 = { acc[0], acc[1], acc[2], acc[3] };
    float4 o2 = { acc[4], acc[5], acc[6], acc[7] };
    *(float4*)(pb + 4*hi) = o1;
    *(float4*)(pb + 8 + 4*hi) = o2;
    if (hi == 0) pl[((size_t)z * (BATCH*NH) + bh) * S_LEN + qrow] = acc[8];
}

// ---------------- Kernel 3: combine + FC (ctx @ Wfc) + LayerNorm -----------
// 4 rows per block; combine of split-K partials happens while staging cs.
__global__ __launch_bounds__(256) void fc_ln(
    const float* __restrict__ pacc, const float* __restrict__ pl, int ns,
    const float* __restrict__ Wfc,
    const float* __restrict__ gamma, const float* __restrict__ beta,
    float* __restrict__ out)
{
    __shared__ float cs[4][DP];
    __shared__ float ys[4][256];
    __shared__ float red[8];
    const int t = threadIdx.x;
    const int row0 = blockIdx.x * 4;

    {
        const int idx = t * 2;
        const int r = idx >> 7, k = idx & 127;
        const int grow = row0 + r;
        const int b = grow >> 11, q = grow & (S_LEN - 1);
        const int h = k >> 4, d0 = k & 15;
        float sx = 0.f, sy = 0.f, L = 0.f;
        for (int z = 0; z < ns; ++z) {
            const size_t o = ((size_t)z * (BATCH*NH) + b * NH + h) * S_LEN + q;
            const float2 a = *(const float2*)(pacc + o * 16 + d0);
            sx += a.x; sy += a.y; L += pl[o];
        }
        const float inv = 1.0f / L;
        cs[r][k]     = sx * inv;
        cs[r][k + 1] = sy * inv;
    }
    __syncthreads();

    float acc[4] = {0,0,0,0};
    for (int k = 0; k < DP; k += 4) {
        const float w0 = Wfc[(k+0)*DM + t];
        const float w1 = Wfc[(k+1)*DM + t];
        const float w2 = Wfc[(k+2)*DM + t];
        const float w3 = Wfc[(k+3)*DM + t];
        #pragma unroll
        for (int r = 0; r < 4; ++r) {
            float4 x = *(const float4*)&cs[r][k];
            acc[r] = fmaf(x.x, w0, fmaf(x.y, w1, fmaf(x.z, w2, fmaf(x.w, w3, acc[r]))));
        }
    }

    #pragma unroll
    for (int r = 0; r < 4; ++r) ys[r][t] = acc[r];
    __syncthreads();

    const int w = t >> 6, lj = t & 63;
    {
        float a0 = ys[w][lj], a1 = ys[w][lj+64], a2 = ys[w][lj+128], a3 = ys[w][lj+192];
        float s1 = a0 + a1 + a2 + a3;
        float s2 = a0*a0 + a1*a1 + a2*a2 + a3*a3;
        #pragma unroll
        for (int off = 32; off; off >>= 1) {
            s1 += __shfl_xor(s1, off);
            s2 += __shfl_xor(s2, off);
        }
        if (lj == 0) {
            float mu = s1 * (1.0f/256.0f);
            float var = s2 * (1.0f/256.0f) - mu*mu;
            red[w*2]     = mu;
            red[w*2 + 1] = rsqrtf(var + 1e-5f);
        }
    }
    __syncthreads();

    const float g = gamma[t], be = beta[t];
    #pragma unroll
    for (int r = 0; r < 4; ++r) {
        float y = (acc[r] - red[r*2]) * red[r*2 + 1];
        out[(size_t)(row0 + r) * DM + t] = fmaf(y, g, be);
    }
}

extern "C" void kernel_launch(void* const* d_in, const int* in_sizes, int n_in,
                              void* d_out, int out_size, void* d_ws, size_t ws_size,
                              hipStream_t stream)
{
    const float* Xq = (const float*)d_in[0];
    const float* Xk = (const float*)d_in[1];
    const float* Xv = (const float*)d_in[2];
    const void* mask_raw = d_in[3];
    const float* Wq  = (const float*)d_in[4];
    const float* Wk  = (const float*)d_in[5];
    const float* Wv  = (const float*)d_in[6];
    const float* Wfc = (const float*)d_in[7];
    const float* gamma = (const float*)d_in[8];
    const float* beta  = (const float*)d_in[9];
    float* out = (float*)d_out;

    const size_t headsz = (size_t)BATCH * NH * S_LEN * DK;      // 1,048,576 elems
    const size_t maskelems = (size_t)BATCH * S_LEN * S_LEN;     // 16.8M

    char* wsb = (char*)d_ws;
    short* Qb = (short*)wsb;                              // 2 MB
    short* Kb = Qb + headsz;                              // 2 MB
    short* Vb = Kb + headsz;                              // 4 MB ([bh][32][S])
    unsigned short* msk = (unsigned short*)(Vb + 2 * headsz);   // 2 MB scrambled bitmask
    char* R = (char*)(msk + maskelems / 16);              // overlap region

    // phase A (proj): Wt [3][128][256] bf16 + flag
    short* Wt = (short*)R;                                // 192 KB
    int* flag = (int*)(Wt + 3 * 128 * 256);
    const size_t phaseA_bytes = (size_t)3*128*256*2 + 4;
    // phase B (attn+): pacc/pl alias the same region
    float* pacc = (float*)R;
    const size_t fixed_bytes = (size_t)(R - wsb);
    size_t ns = 4;
    while (ns > 1) {
        size_t phaseB = ns * ((size_t)BATCH*NH*S_LEN*17*4);
        size_t need = fixed_bytes + (phaseB > phaseA_bytes ? phaseB : phaseA_bytes);
        if (need <= ws_size) break;
        ns >>= 1;
    }
    float* pl = pacc + ns * (size_t)BATCH * NH * S_LEN * 16;

    vinit<<<dim3(512), dim3(256), 0, stream>>>(Vb, flag);     // also zeroes flag
    detect_mask_dtype<<<dim3(1024), dim3(256), 0, stream>>>((const unsigned int*)mask_raw, flag);
    pack_mask<<<dim3(maskelems / 1024), dim3(256), 0, stream>>>(
        mask_raw, (unsigned long long*)msk, flag);
    cvt_w<<<dim3(384), dim3(256), 0, stream>>>(Wq, Wk, Wv, Wt);

    proj_mfma<<<dim3(BATCH * S_LEN / 32, 3), dim3(256), 0, stream>>>(Xq, Xk, Xv, Wt, Qb, Kb, Vb);
    attn_mfma<<<dim3(S_LEN / 128, BATCH * NH, (unsigned)ns), dim3(256), 0, stream>>>(
        Qb, Kb, Vb, (const unsigned int*)msk, pacc, pl);
    fc_ln<<<dim3(BATCH * S_LEN / 4), dim3(256), 0, stream>>>(pacc, pl, (int)ns, Wfc, gamma, beta, out);
}

// Round 11
// 85.714 us; speedup vs baseline: 3.3156x; 1.0988x over previous
//
#include <hip/hip_runtime.h>
#include <hip/hip_bf16.h>

#define S_LEN 2048
#define BATCH 4
#define NH 8
#define DK 16
#define DM 256
#define DP 128           // NH*DK
#define L2E 1.4426950408889634f
#define MAGIC_BOOL 0x600DB001

typedef short bf16x8 __attribute__((ext_vector_type(8)));
typedef short short4v __attribute__((ext_vector_type(4)));
typedef float f32x16 __attribute__((ext_vector_type(16)));

__device__ __forceinline__ short f2bf(float x) {
    __hip_bfloat16 h = __float2bfloat16(x);
    return __builtin_bit_cast(short, h);
}

union Frag { bf16x8 v; short4v h2[2]; };

// ---------------- Kernel A: setup = mask-dtype detect + W->bf16^T ----------
// blocks [0,1024): detect over first 1MB (store MAGIC if bool evidence;
// no init needed - poison/stale values are never MAGIC unless bool, and
// detection is deterministic per input). blocks [1024,1408): cvt_w.
__global__ __launch_bounds__(256) void setup(
    const unsigned int* __restrict__ mrawu, int* __restrict__ flag,
    const float* __restrict__ Wq, const float* __restrict__ Wk,
    const float* __restrict__ Wv, short* __restrict__ Wt)
{
    const int bi = blockIdx.x;
    if (bi < 1024) {
        unsigned int u = mrawu[bi * 256 + threadIdx.x];   // in-bounds for both dtypes
        if (u & 0xFFFFFF00u) *flag = MAGIC_BOOL;          // benign same-value race
    } else {
        const int tid = (bi - 1024) * 256 + threadIdx.x;  // 98304
        const int m = tid >> 15;
        const int rem = tid & 32767;
        const int k = rem >> 7, c = rem & 127;
        const float* W = (m == 0) ? Wq : (m == 1) ? Wk : Wv;
        const float scale = (m == 0) ? 0.25f * L2E : 1.0f;  // fold 1/sqrt(dk)*log2e into Wq
        Wt[((size_t)m * 128 + c) * 256 + k] = f2bf(W[(size_t)k * 128 + c] * scale);
    }
}

// ---------------- Kernel B: phase1 = proj_mfma U vinit U pack_mask ---------
// blocks [0,768): proj (starts first - the compute-heavy role)
// blocks [768,1280): vinit (V ones-rows 16,20 = 1.0)
// blocks [1280,17664): pack (mask -> scrambled bitmask, MLP 4 groups/wave)
__global__ __launch_bounds__(256) void phase1(
    const void* __restrict__ mraw, const int* __restrict__ flag,
    unsigned long long* __restrict__ ms64,
    const float* __restrict__ Xq, const float* __restrict__ Xk, const float* __restrict__ Xv,
    const short* __restrict__ Wt,
    short* __restrict__ Qb, short* __restrict__ Kb, short* __restrict__ Vb)
{
    __shared__ short xs_s[32 * 260];            // proj only; pitch 260 (2-way free)
    const int bi = blockIdx.x;
    const int t = threadIdx.x;

    if (bi < 768) {
        // ---------------- proj_mfma ----------------
        const int inp = bi >> 8;                // 0=Q,1=K,2=V
        const int s0 = (bi & 255) * 32;
        {
            const float* xsrc = ((inp == 0) ? Xq : (inp == 1) ? Xk : Xv)
                              + (size_t)(s0 + (t >> 3)) * 256 + (t & 7) * 32;
            short* xdst = &xs_s[(t >> 3) * 260 + (t & 7) * 32];
            #pragma unroll
            for (int u = 0; u < 8; ++u) {
                float4 xv = *(const float4*)(xsrc + u * 4);
                short4v o = { f2bf(xv.x), f2bf(xv.y), f2bf(xv.z), f2bf(xv.w) };
                *(short4v*)(xdst + u * 4) = o;
            }
        }
        __syncthreads();

        const int wave = t >> 6, lane = t & 63;
        const int lq = lane & 31, hi = lane >> 5;
        const int c = wave * 32 + lq;           // out col 0..127
        const short* wrow = Wt + ((size_t)inp * 128 + c) * 256;

        f32x16 acc;
        #pragma unroll
        for (int i = 0; i < 16; ++i) acc[i] = 0.f;

        #pragma unroll
        for (int kb = 0; kb < 16; ++kb) {
            Frag af, bf_;
            af.h2[0]  = *(const short4v*)&xs_s[lq * 260 + kb*16 + 4*hi];
            af.h2[1]  = *(const short4v*)&xs_s[lq * 260 + kb*16 + 8 + 4*hi];
            bf_.h2[0] = *(const short4v*)(wrow + kb*16 + 4*hi);
            bf_.h2[1] = *(const short4v*)(wrow + kb*16 + 8 + 4*hi);
            acc = __builtin_amdgcn_mfma_f32_32x32x16_bf16(af.v, bf_.v, acc, 0, 0, 0);
        }

        // D: col(lane&31)=c, row(reg r)=s0 + (r&3)+8*(r>>2)+4*hi
        const int b = s0 >> 11, sl = s0 & (S_LEN - 1);
        const int h = c >> 4, d = c & 15;
        if (inp < 2) {
            short* dst = (inp == 0) ? Qb : Kb;
            #pragma unroll
            for (int r = 0; r < 16; ++r) {
                const int s = sl + (r & 3) + 8*(r >> 2) + 4*hi;
                dst[(((size_t)(b * NH + h)) * S_LEN + s) * DK + d] = f2bf(acc[r]);
            }
        } else {
            short* vb = Vb + (((size_t)(b * NH + h)) * 32 + d) * S_LEN + sl;
            #pragma unroll
            for (int g = 0; g < 4; ++g) {
                short4v vv = { f2bf(acc[4*g]), f2bf(acc[4*g+1]), f2bf(acc[4*g+2]), f2bf(acc[4*g+3]) };
                *(short4v*)(vb + 8*g + 4*hi) = vv;
            }
        }
    } else if (bi < 1280) {
        // ---------------- vinit ----------------
        const int tid = (bi - 768) * 256 + t;   // 131072 total
        const int bh = tid >> 12;
        const int rem = tid & 4095;
        const int row = 16 + (rem >> 11) * 4;   // 16 or 20
        const int s = rem & 2047;
        Vb[((size_t)bh * 32 + row) * S_LEN + s] = (short)0x3F80;  // bf16 1.0
    } else {
        // ---------------- pack_mask ----------------
        // u64 layout [tile][row][w0h]; bit j = key 32*(j>>5)+4*((j>>4)&1)+8*((j>>2)&3)+(j&3)
        const int lane = t & 63;
        const size_t kbase = ((size_t)(bi - 1280) * 4 + (t >> 6)) * 256;
        const int isInt = (*flag != MAGIC_BOOL);

        int v[4];
        if (isInt) {
            const int* p = (const int*)mraw + kbase + lane;
            #pragma unroll
            for (int g = 0; g < 4; ++g) v[g] = p[g * 64];
        } else {
            const unsigned char* p = (const unsigned char*)mraw + kbase + lane;
            #pragma unroll
            for (int g = 0; g < 4; ++g) v[g] = p[g * 64];
        }

        const int src = 32*((lane>>5)&1) + 4*((lane>>4)&1) + 8*((lane>>2)&3) + (lane&3);
        const size_t row = kbase >> 11;         // b*S + q
        const int koff0 = (int)(kbase & 2047);

        #pragma unroll
        for (int g = 0; g < 4; ++g) {
            const unsigned long long W = __ballot(v[g] != 0);
            const unsigned long long W2 = __ballot((int)((W >> src) & 1ull));
            if (lane == 0) {
                const int koff = koff0 + g * 64;
                ms64[(size_t)(koff >> 7) * (BATCH*S_LEN*2) + row*2 + ((koff >> 6) & 1)] = W2;
            }
        }
    }
}

// ---------------- Kernel C: MFMA flash attention, LDS-staged K/V -----------
// grid (S/128, B*H, ns); block 256 = 4 waves x 32 q-rows.
__global__ __launch_bounds__(256, 8) void attn_mfma(
    const short* __restrict__ Qb, const short* __restrict__ Kb, const short* __restrict__ Vb,
    const unsigned int* __restrict__ ms, float* __restrict__ pacc, float* __restrict__ pl)
{
    __shared__ short kt_s[128 * 20];   // K tile: pitch 20 shorts (10 dw)
    __shared__ short vt_s[32 * 132];   // V^T tile: pitch 132 shorts (66 dw)

    const int bh = blockIdx.y;
    const int b = bh >> 3;
    const int z = blockIdx.z;
    const int t = threadIdx.x;
    const int wave = t >> 6, lane = t & 63;
    const int lq = lane & 31, hi = lane >> 5;
    const int qrow = blockIdx.x * 128 + wave * 32 + lq;
    const int hish = hi * 16;

    Frag qf;
    {
        const short* qp = Qb + ((size_t)bh * S_LEN + qrow) * DK;
        qf.h2[0] = *(const short4v*)(qp + 4*hi);
        qf.h2[1] = *(const short4v*)(qp + 8 + 4*hi);
    }

    f32x16 acc;
    #pragma unroll
    for (int i = 0; i < 16; ++i) acc[i] = 0.f;

    const short* kbase = Kb + (size_t)bh * S_LEN * DK;
    const short* vbase = Vb + (size_t)bh * 32 * S_LEN;
    const unsigned int* mbase = ms + ((size_t)b * S_LEN + qrow) * 4;

    const int tiles = (S_LEN / 128) / gridDim.z;
    const int t0 = z * tiles, t1 = t0 + tiles;

    for (int tile = t0; tile < t1; ++tile) {
        const int k0 = tile * 128;

        // ---- stage K tile (4KB, contiguous) and V^T tile (8KB, 256B rows)
        {
            const uint4 kv = *(const uint4*)(kbase + (size_t)k0 * DK + t * 8);
            short* kdst = &kt_s[(t >> 1) * 20 + (t & 1) * 8];
            *(uint2*)(kdst)     = *(uint2*)&kv;
            *(uint2*)(kdst + 4) = *((uint2*)&kv + 1);

            const short* vsrc = vbase + (size_t)(t >> 3) * S_LEN + k0 + (t & 7) * 16;
            uint4 v0 = *(const uint4*)(vsrc);
            uint4 v1 = *(const uint4*)(vsrc + 8);
            short* vdst = &vt_s[(t >> 3) * 132 + (t & 7) * 16];
            *(uint2*)(vdst)      = *(uint2*)&v0;
            *(uint2*)(vdst + 4)  = *((uint2*)&v0 + 1);
            *(uint2*)(vdst + 8)  = *(uint2*)&v1;
            *(uint2*)(vdst + 12) = *((uint2*)&v1 + 1);
        }
        __syncthreads();

        const uint4 mw = *(const uint4*)(mbase + (size_t)tile * (BATCH * S_LEN * 4));

        #pragma unroll
        for (int kt = 0; kt < 4; ++kt) {
            // mask -> C-init: -100 where masked (bit order matches D layout)
            const unsigned int W = ((kt==0)?mw.x:(kt==1)?mw.y:(kt==2)?mw.z:mw.w) >> hish;
            f32x16 ci;
            #pragma unroll
            for (int r = 0; r < 16; ++r)
                ci[r] = __int_as_float(((int)(W << (31 - r)) >> 31) & 0xC2C80000);

            // QK^T for 32 keys (log2-domain scores via scaled Wq)
            Frag kf;
            kf.h2[0] = *(const short4v*)&kt_s[(kt*32 + lq) * 20 + 4*hi];
            kf.h2[1] = *(const short4v*)&kt_s[(kt*32 + lq) * 20 + 8 + 4*hi];
            f32x16 p = __builtin_amdgcn_mfma_f32_32x32x16_bf16(kf.v, qf.v, ci, 0, 0, 0);

            #pragma unroll
            for (int r = 0; r < 16; ++r) p[r] = __builtin_amdgcn_exp2f(p[r]);

            // PV: 2 MFMAs of 16 keys; P^T regs feed B-frag directly
            #pragma unroll
            for (int j = 0; j < 2; ++j) {
                union { bf16x8 v; short s[8]; } pf;
                #pragma unroll
                for (int e = 0; e < 8; ++e) pf.s[e] = f2bf(p[j*8 + e]);
                Frag vf;
                const int vo = lq * 132 + (kt*2 + j) * 16 + 4*hi;
                vf.h2[0] = *(const short4v*)&vt_s[vo];
                vf.h2[1] = *(const short4v*)&vt_s[vo + 8];
                acc = __builtin_amdgcn_mfma_f32_32x32x16_bf16(vf.v, pf.v, acc, 0, 0, 0);
            }
        }
        __syncthreads();   // protect LDS before next tile's stage
    }

    // partial store (unnormalized); acc[8] = sum of P (ones-row of V)
    float* pb = pacc + (((size_t)z * (BATCH*NH) + bh) * S_LEN + qrow) * 16;
    float4 o1 = { acc[0], acc[1], acc[2], acc[3] };
    float4 o2 = { acc[4], acc[5], acc[6], acc[7] };
    *(float4*)(pb + 4*hi) = o1;
    *(float4*)(pb + 8 + 4*hi) = o2;
    if (hi == 0) pl[((size_t)z * (BATCH*NH) + bh) * S_LEN + qrow] = acc[8];
}

// ---------------- Kernel D: combine + FC (ctx @ Wfc) + LayerNorm -----------
// 8 rows per block (halves Wfc L2 re-reads); combine folded into staging.
__global__ __launch_bounds__(256) void fc_ln(
    const float* __restrict__ pacc, const float* __restrict__ pl, int ns,
    const float* __restrict__ Wfc,
    const float* __restrict__ gamma, const float* __restrict__ beta,
    float* __restrict__ out)
{
    __shared__ float cs[8][DP];
    __shared__ float ys[8][256];
    __shared__ float red[16];
    const int t = threadIdx.x;
    const int row0 = blockIdx.x * 8;

    {
        const int idx = t * 4;
        const int r = idx >> 7, k = idx & 127;       // r 0..7, k mult of 4
        const int grow = row0 + r;
        const int b = grow >> 11, q = grow & (S_LEN - 1);
        const int h = k >> 4, d0 = k & 15;           // d0 in {0,4,8,12}
        float4 s = {0.f, 0.f, 0.f, 0.f};
        float L = 0.f;
        for (int z = 0; z < ns; ++z) {
            const size_t o = ((size_t)z * (BATCH*NH) + b * NH + h) * S_LEN + q;
            const float4 a = *(const float4*)(pacc + o * 16 + d0);
            s.x += a.x; s.y += a.y; s.z += a.z; s.w += a.w;
            L += pl[o];
        }
        const float inv = 1.0f / L;
        float4 o4 = { s.x * inv, s.y * inv, s.z * inv, s.w * inv };
        *(float4*)&cs[r][k] = o4;
    }
    __syncthreads();

    float acc[8] = {0,0,0,0,0,0,0,0};
    for (int k = 0; k < DP; k += 4) {
        const float w0 = Wfc[(k+0)*DM + t];
        const float w1 = Wfc[(k+1)*DM + t];
        const float w2 = Wfc[(k+2)*DM + t];
        const float w3 = Wfc[(k+3)*DM + t];
        #pragma unroll
        for (int r = 0; r < 8; ++r) {
            float4 x = *(const float4*)&cs[r][k];
            acc[r] = fmaf(x.x, w0, fmaf(x.y, w1, fmaf(x.z, w2, fmaf(x.w, w3, acc[r]))));
        }
    }

    #pragma unroll
    for (int r = 0; r < 8; ++r) ys[r][t] = acc[r];
    __syncthreads();

    const int w = t >> 6, lj = t & 63;
    #pragma unroll
    for (int rr = 0; rr < 2; ++rr) {
        const int r = w * 2 + rr;
        float a0 = ys[r][lj], a1 = ys[r][lj+64], a2 = ys[r][lj+128], a3 = ys[r][lj+192];
        float s1 = a0 + a1 + a2 + a3;
        float s2 = a0*a0 + a1*a1 + a2*a2 + a3*a3;
        #pragma unroll
        for (int off = 32; off; off >>= 1) {
            s1 += __shfl_xor(s1, off);
            s2 += __shfl_xor(s2, off);
        }
        if (lj == 0) {
            float mu = s1 * (1.0f/256.0f);
            float var = s2 * (1.0f/256.0f) - mu*mu;
            red[r*2]     = mu;
            red[r*2 + 1] = rsqrtf(var + 1e-5f);
        }
    }
    __syncthreads();

    const float g = gamma[t], be = beta[t];
    #pragma unroll
    for (int r = 0; r < 8; ++r) {
        float y = (acc[r] - red[r*2]) * red[r*2 + 1];
        out[(size_t)(row0 + r) * DM + t] = fmaf(y, g, be);
    }
}

extern "C" void kernel_launch(void* const* d_in, const int* in_sizes, int n_in,
                              void* d_out, int out_size, void* d_ws, size_t ws_size,
                              hipStream_t stream)
{
    const float* Xq = (const float*)d_in[0];
    const float* Xk = (const float*)d_in[1];
    const float* Xv = (const float*)d_in[2];
    const void* mask_raw = d_in[3];
    const float* Wq  = (const float*)d_in[4];
    const float* Wk  = (const float*)d_in[5];
    const float* Wv  = (const float*)d_in[6];
    const float* Wfc = (const float*)d_in[7];
    const float* gamma = (const float*)d_in[8];
    const float* beta  = (const float*)d_in[9];
    float* out = (float*)d_out;

    const size_t headsz = (size_t)BATCH * NH * S_LEN * DK;      // 1,048,576 elems
    const size_t maskelems = (size_t)BATCH * S_LEN * S_LEN;     // 16.8M

    char* wsb = (char*)d_ws;
    short* Qb = (short*)wsb;                              // 2 MB
    short* Kb = Qb + headsz;                              // 2 MB
    short* Vb = Kb + headsz;                              // 4 MB ([bh][32][S])
    unsigned short* msk = (unsigned short*)(Vb + 2 * headsz);   // 2 MB scrambled bitmask
    short* Wt = (short*)(msk + maskelems / 16);           // 192 KB
    float* pacc = (float*)(Wt + 3 * 128 * 256);
    size_t ns = 4;
    {
        const size_t fixed = (size_t)((char*)pacc - wsb);
        while (ns > 1 && fixed + ns * ((size_t)BATCH*NH*S_LEN*17*4) + 64 > ws_size)
            ns >>= 1;
    }
    float* pl = pacc + ns * (size_t)BATCH * NH * S_LEN * 16;
    int* flag = (int*)(pl + ns * (size_t)BATCH * NH * S_LEN);

    setup<<<dim3(1408), dim3(256), 0, stream>>>(
        (const unsigned int*)mask_raw, flag, Wq, Wk, Wv, Wt);
    phase1<<<dim3(768 + 512 + (unsigned)(maskelems / 1024)), dim3(256), 0, stream>>>(
        mask_raw, flag, (unsigned long long*)msk, Xq, Xk, Xv, Wt, Qb, Kb, Vb);
    attn_mfma<<<dim3(S_LEN / 128, BATCH * NH, (unsigned)ns), dim3(256), 0, stream>>>(
        Qb, Kb, Vb, (const unsigned int*)msk, pacc, pl);
    fc_ln<<<dim3(BATCH * S_LEN / 8), dim3(256), 0, stream>>>(pacc, pl, (int)ns, Wfc, gamma, beta, out);
}

// Round 12
// 81.651 us; speedup vs baseline: 3.4805x; 1.0498x over previous
//
#include <hip/hip_runtime.h>
#include <hip/hip_bf16.h>

#define S_LEN 2048
#define BATCH 4
#define NH 8
#define DK 16
#define DM 256
#define DP 128           // NH*DK
#define L2E 1.4426950408889634f
#define MAGIC_BOOL 0x600DB001

typedef short bf16x8 __attribute__((ext_vector_type(8)));
typedef short short4v __attribute__((ext_vector_type(4)));
typedef float f32x16 __attribute__((ext_vector_type(16)));

__device__ __forceinline__ short f2bf(float x) {
    __hip_bfloat16 h = __float2bfloat16(x);
    return __builtin_bit_cast(short, h);
}

union Frag { bf16x8 v; short4v h2[2]; };

// ---------------- Kernel A: setup = mask-dtype detect + W->bf16^T ----------
__global__ __launch_bounds__(256) void setup(
    const unsigned int* __restrict__ mrawu, int* __restrict__ flag,
    const float* __restrict__ Wq, const float* __restrict__ Wk,
    const float* __restrict__ Wv, short* __restrict__ Wt)
{
    const int bi = blockIdx.x;
    if (bi < 1024) {
        unsigned int u = mrawu[bi * 256 + threadIdx.x];   // first 1MB, in-bounds either dtype
        if (u & 0xFFFFFF00u) *flag = MAGIC_BOOL;          // benign same-value race
    } else {
        const int tid = (bi - 1024) * 256 + threadIdx.x;  // 98304
        const int m = tid >> 15;
        const int rem = tid & 32767;
        const int k = rem >> 7, c = rem & 127;
        const float* W = (m == 0) ? Wq : (m == 1) ? Wk : Wv;
        const float scale = (m == 0) ? 0.25f * L2E : 1.0f;  // fold 1/sqrt(dk)*log2e into Wq
        Wt[((size_t)m * 128 + c) * 256 + k] = f2bf(W[(size_t)k * 128 + c] * scale);
    }
}

// ---------------- Kernel B: phase1 = proj_mfma U vinit U pack_mask ---------
// blocks [0,768): proj;  [768,1280): vinit;  [1280,5376): pack (plain bits)
__global__ __launch_bounds__(256) void phase1(
    const void* __restrict__ mraw, const int* __restrict__ flag,
    unsigned long long* __restrict__ ms64,
    const float* __restrict__ Xq, const float* __restrict__ Xk, const float* __restrict__ Xv,
    const short* __restrict__ Wt,
    short* __restrict__ Qt, short* __restrict__ Kb, short* __restrict__ Vb)
{
    __shared__ short xs_s[32 * 260];            // proj only; pitch 260 (2-way free)
    const int bi = blockIdx.x;
    const int t = threadIdx.x;

    if (bi < 768) {
        // ---------------- proj_mfma ----------------
        const int inp = bi >> 8;                // 0=Q,1=K,2=V
        const int s0 = (bi & 255) * 32;
        {
            // coalesced: each wave-load instruction covers one full 1KB X row
            const float* xbase = ((inp == 0) ? Xq : (inp == 1) ? Xk : Xv) + (size_t)s0 * 256;
            #pragma unroll
            for (int u = 0; u < 8; ++u) {
                const int idx = u * 1024 + t * 4;       // linear float index in 32x256 tile
                const int row = idx >> 8, col = idx & 255;
                float4 xv = *(const float4*)(xbase + idx);
                short4v o = { f2bf(xv.x), f2bf(xv.y), f2bf(xv.z), f2bf(xv.w) };
                *(short4v*)&xs_s[row * 260 + col] = o;
            }
        }
        __syncthreads();

        const int wave = t >> 6, lane = t & 63;
        const int lq = lane & 31, hi = lane >> 5;
        const int c = wave * 32 + lq;           // out col 0..127
        const short* wrow = Wt + ((size_t)inp * 128 + c) * 256;

        f32x16 acc;
        #pragma unroll
        for (int i = 0; i < 16; ++i) acc[i] = 0.f;

        #pragma unroll
        for (int kb = 0; kb < 16; ++kb) {
            Frag af, bf_;
            af.h2[0]  = *(const short4v*)&xs_s[lq * 260 + kb*16 + 4*hi];
            af.h2[1]  = *(const short4v*)&xs_s[lq * 260 + kb*16 + 8 + 4*hi];
            bf_.h2[0] = *(const short4v*)(wrow + kb*16 + 4*hi);
            bf_.h2[1] = *(const short4v*)(wrow + kb*16 + 8 + 4*hi);
            acc = __builtin_amdgcn_mfma_f32_32x32x16_bf16(af.v, bf_.v, acc, 0, 0, 0);
        }

        // D: col(lane&31)=c, row(reg r)=s0 + (r&3)+8*(r>>2)+4*hi
        const int b = s0 >> 11, sl = s0 & (S_LEN - 1);
        const int h = c >> 4, d = c & 15;
        if (inp == 1) {
            // K: [bh][S][16] (attn stages K-tiles contiguously)
            #pragma unroll
            for (int r = 0; r < 16; ++r) {
                const int s = sl + (r & 3) + 8*(r >> 2) + 4*hi;
                Kb[(((size_t)(b * NH + h)) * S_LEN + s) * DK + d] = f2bf(acc[r]);
            }
        } else {
            // Q^T: [bh][16][S]; V^T: [bh][32][S] -- coalesced 8B stores
            short* base = (inp == 0)
                ? Qt + (((size_t)(b * NH + h)) * 16 + d) * S_LEN + sl
                : Vb + (((size_t)(b * NH + h)) * 32 + d) * S_LEN + sl;
            #pragma unroll
            for (int g = 0; g < 4; ++g) {
                short4v vv = { f2bf(acc[4*g]), f2bf(acc[4*g+1]), f2bf(acc[4*g+2]), f2bf(acc[4*g+3]) };
                *(short4v*)(base + 8*g + 4*hi) = vv;
            }
        }
    } else if (bi < 1280) {
        // ---------------- vinit ----------------
        const int tid = (bi - 768) * 256 + t;   // 131072 total
        const int bh = tid >> 12;
        const int rem = tid & 4095;
        const int row = 16 + (rem >> 11) * 4;   // 16 or 20
        const int s = rem & 2047;
        Vb[((size_t)bh * 32 + row) * S_LEN + s] = (short)0x3F80;  // bf16 1.0
    } else {
        // ---------------- pack_mask: plain ballot bits, tile-major ----------
        // u64 at [tile][row][w0h]; bit j = mask[row][tile*128 + 64*w0h + j]
        const int lane = t & 63;
        const size_t kbase = ((size_t)(bi - 1280) * 4 + (t >> 6)) * 1024;  // 16 groups/wave
        const int isInt = (*flag != MAGIC_BOOL);

        int v[16];
        if (isInt) {
            const int* p = (const int*)mraw + kbase + lane;
            #pragma unroll
            for (int g = 0; g < 16; ++g) v[g] = p[g * 64];
        } else {
            const unsigned char* p = (const unsigned char*)mraw + kbase + lane;
            #pragma unroll
            for (int g = 0; g < 16; ++g) v[g] = p[g * 64];
        }

        const size_t row = kbase >> 11;         // b*S + q
        const int koff0 = (int)(kbase & 2047);

        #pragma unroll
        for (int g = 0; g < 16; ++g) {
            const unsigned long long W = __ballot(v[g] != 0);
            if (lane == 0) {
                const int koff = koff0 + g * 64;
                ms64[(size_t)(koff >> 7) * (BATCH*S_LEN*2) + row*2 + ((koff >> 6) & 1)] = W;
            }
        }
    }
}

// ---------------- Kernel C: MFMA flash attention, LDS-staged K/V -----------
// grid (S/128, B*H, ns); block 256 = 4 waves x 32 q-rows.
__global__ __launch_bounds__(256, 8) void attn_mfma(
    const short* __restrict__ Qt, const short* __restrict__ Kb, const short* __restrict__ Vb,
    const unsigned long long* __restrict__ ms64, float* __restrict__ pacc, float* __restrict__ pl)
{
    __shared__ short kt_s[128 * 20];   // K tile: pitch 20 shorts (10 dw)
    __shared__ short vt_s[32 * 132];   // V^T tile: pitch 132 shorts (66 dw)

    const int bh = blockIdx.y;
    const int b = bh >> 3;
    const int z = blockIdx.z;
    const int t = threadIdx.x;
    const int wave = t >> 6, lane = t & 63;
    const int lq = lane & 31, hi = lane >> 5;
    const int qrow = blockIdx.x * 128 + wave * 32 + lq;

    Frag qf;
    {
        // Q^T [bh][16][S]: 8 scalar reads, coalesced across lanes (qrow = ..+lq)
        const short* qt = Qt + (size_t)bh * 16 * S_LEN + qrow;
        #pragma unroll
        for (int j = 0; j < 4; ++j) {
            qf.h2[0][j] = qt[(size_t)(4*hi + j) * S_LEN];
            qf.h2[1][j] = qt[(size_t)(8 + 4*hi + j) * S_LEN];
        }
    }

    f32x16 acc;
    #pragma unroll
    for (int i = 0; i < 16; ++i) acc[i] = 0.f;

    const short* kbase = Kb + (size_t)bh * S_LEN * DK;
    const short* vbase = Vb + (size_t)bh * 32 * S_LEN;
    const unsigned long long* mbase = ms64 + ((size_t)b * S_LEN + qrow) * 2;

    const int tiles = (S_LEN / 128) / gridDim.z;
    const int t0 = z * tiles, t1 = t0 + tiles;

    for (int tile = t0; tile < t1; ++tile) {
        const int k0 = tile * 128;

        // ---- stage K tile (4KB, contiguous) and V^T tile (8KB, 256B rows)
        {
            const uint4 kv = *(const uint4*)(kbase + (size_t)k0 * DK + t * 8);
            short* kdst = &kt_s[(t >> 1) * 20 + (t & 1) * 8];
            *(uint2*)(kdst)     = *(uint2*)&kv;
            *(uint2*)(kdst + 4) = *((uint2*)&kv + 1);

            const short* vsrc = vbase + (size_t)(t >> 3) * S_LEN + k0 + (t & 7) * 16;
            uint4 v0 = *(const uint4*)(vsrc);
            uint4 v1 = *(const uint4*)(vsrc + 8);
            short* vdst = &vt_s[(t >> 3) * 132 + (t & 7) * 16];
            *(uint2*)(vdst)      = *(uint2*)&v0;
            *(uint2*)(vdst + 4)  = *((uint2*)&v0 + 1);
            *(uint2*)(vdst + 8)  = *(uint2*)&v1;
            *(uint2*)(vdst + 12) = *((uint2*)&v1 + 1);
        }
        __syncthreads();

        // two plain-bit u64 words cover this 128-key tile
        const unsigned long long* mw = mbase + (size_t)tile * (BATCH * S_LEN * 2);
        const unsigned long long W64a = mw[0], W64b = mw[1];

        #pragma unroll
        for (int kt = 0; kt < 4; ++kt) {
            // mask bits: key(r) = 32*(kt&1) + 4*hi + (r&3)+8*(r>>2) within word kt>>1
            const unsigned int W = (unsigned int)(((kt < 2) ? W64a : W64b)
                                                  >> (32*(kt & 1) + 4*hi));
            f32x16 ci;
            #pragma unroll
            for (int r = 0; r < 16; ++r) {
                const int bit = (r & 3) + 8*(r >> 2);
                ci[r] = __int_as_float(((int)(W << (31 - bit)) >> 31) & 0xC2C80000);
            }

            // QK^T for 32 keys (log2-domain scores via scaled Wq)
            Frag kf;
            kf.h2[0] = *(const short4v*)&kt_s[(kt*32 + lq) * 20 + 4*hi];
            kf.h2[1] = *(const short4v*)&kt_s[(kt*32 + lq) * 20 + 8 + 4*hi];
            f32x16 p = __builtin_amdgcn_mfma_f32_32x32x16_bf16(kf.v, qf.v, ci, 0, 0, 0);

            #pragma unroll
            for (int r = 0; r < 16; ++r) p[r] = __builtin_amdgcn_exp2f(p[r]);

            // PV: 2 MFMAs of 16 keys; P^T regs feed B-frag directly
            #pragma unroll
            for (int j = 0; j < 2; ++j) {
                union { bf16x8 v; short s[8]; } pf;
                #pragma unroll
                for (int e = 0; e < 8; ++e) pf.s[e] = f2bf(p[j*8 + e]);
                Frag vf;
                const int vo = lq * 132 + (kt*2 + j) * 16 + 4*hi;
                vf.h2[0] = *(const short4v*)&vt_s[vo];
                vf.h2[1] = *(const short4v*)&vt_s[vo + 8];
                acc = __builtin_amdgcn_mfma_f32_32x32x16_bf16(vf.v, pf.v, acc, 0, 0, 0);
            }
        }
        __syncthreads();   // protect LDS before next tile's stage
    }

    // partial store (unnormalized); acc[8] = sum of P (ones-row of V)
    float* pb = pacc + (((size_t)z * (BATCH*NH) + bh) * S_LEN + qrow) * 16;
    float4 o1 = { acc[0], acc[1], acc[2], acc[3] };
    float4 o2 = { acc[4], acc[5], acc[6], acc[7] };
    *(float4*)(pb + 4*hi) = o1;
    *(float4*)(pb + 8 + 4*hi) = o2;
    if (hi == 0) pl[((size_t)z * (BATCH*NH) + bh) * S_LEN + qrow] = acc[8];
}

// ---------------- Kernel D: combine + FC (ctx @ Wfc) + LayerNorm -----------
__global__ __launch_bounds__(256) void fc_ln(
    const float* __restrict__ pacc, const float* __restrict__ pl, int ns,
    const float* __restrict__ Wfc,
    const float* __restrict__ gamma, const float* __restrict__ beta,
    float* __restrict__ out)
{
    __shared__ float cs[8][DP];
    __shared__ float ys[8][256];
    __shared__ float red[16];
    const int t = threadIdx.x;
    const int row0 = blockIdx.x * 8;

    {
        const int idx = t * 4;
        const int r = idx >> 7, k = idx & 127;       // r 0..7, k mult of 4
        const int grow = row0 + r;
        const int b = grow >> 11, q = grow & (S_LEN - 1);
        const int h = k >> 4, d0 = k & 15;           // d0 in {0,4,8,12}
        float4 s = {0.f, 0.f, 0.f, 0.f};
        float L = 0.f;
        for (int z = 0; z < ns; ++z) {
            const size_t o = ((size_t)z * (BATCH*NH) + b * NH + h) * S_LEN + q;
            const float4 a = *(const float4*)(pacc + o * 16 + d0);
            s.x += a.x; s.y += a.y; s.z += a.z; s.w += a.w;
            L += pl[o];
        }
        const float inv = 1.0f / L;
        float4 o4 = { s.x * inv, s.y * inv, s.z * inv, s.w * inv };
        *(float4*)&cs[r][k] = o4;
    }
    __syncthreads();

    float acc[8] = {0,0,0,0,0,0,0,0};
    for (int k = 0; k < DP; k += 4) {
        const float w0 = Wfc[(k+0)*DM + t];
        const float w1 = Wfc[(k+1)*DM + t];
        const float w2 = Wfc[(k+2)*DM + t];
        const float w3 = Wfc[(k+3)*DM + t];
        #pragma unroll
        for (int r = 0; r < 8; ++r) {
            float4 x = *(const float4*)&cs[r][k];
            acc[r] = fmaf(x.x, w0, fmaf(x.y, w1, fmaf(x.z, w2, fmaf(x.w, w3, acc[r]))));
        }
    }

    #pragma unroll
    for (int r = 0; r < 8; ++r) ys[r][t] = acc[r];
    __syncthreads();

    const int w = t >> 6, lj = t & 63;
    #pragma unroll
    for (int rr = 0; rr < 2; ++rr) {
        const int r = w * 2 + rr;
        float a0 = ys[r][lj], a1 = ys[r][lj+64], a2 = ys[r][lj+128], a3 = ys[r][lj+192];
        float s1 = a0 + a1 + a2 + a3;
        float s2 = a0*a0 + a1*a1 + a2*a2 + a3*a3;
        #pragma unroll
        for (int off = 32; off; off >>= 1) {
            s1 += __shfl_xor(s1, off);
            s2 += __shfl_xor(s2, off);
        }
        if (lj == 0) {
            float mu = s1 * (1.0f/256.0f);
            float var = s2 * (1.0f/256.0f) - mu*mu;
            red[r*2]     = mu;
            red[r*2 + 1] = rsqrtf(var + 1e-5f);
        }
    }
    __syncthreads();

    const float g = gamma[t], be = beta[t];
    #pragma unroll
    for (int r = 0; r < 8; ++r) {
        float y = (acc[r] - red[r*2]) * red[r*2 + 1];
        out[(size_t)(row0 + r) * DM + t] = fmaf(y, g, be);
    }
}

extern "C" void kernel_launch(void* const* d_in, const int* in_sizes, int n_in,
                              void* d_out, int out_size, void* d_ws, size_t ws_size,
                              hipStream_t stream)
{
    const float* Xq = (const float*)d_in[0];
    const float* Xk = (const float*)d_in[1];
    const float* Xv = (const float*)d_in[2];
    const void* mask_raw = d_in[3];
    const float* Wq  = (const float*)d_in[4];
    const float* Wk  = (const float*)d_in[5];
    const float* Wv  = (const float*)d_in[6];
    const float* Wfc = (const float*)d_in[7];
    const float* gamma = (const float*)d_in[8];
    const float* beta  = (const float*)d_in[9];
    float* out = (float*)d_out;

    const size_t headsz = (size_t)BATCH * NH * S_LEN * DK;      // 1,048,576 elems
    const size_t maskelems = (size_t)BATCH * S_LEN * S_LEN;     // 16.8M

    char* wsb = (char*)d_ws;
    short* Qt = (short*)wsb;                              // 2 MB ([bh][16][S] transposed)
    short* Kb = Qt + headsz;                              // 2 MB ([bh][S][16])
    short* Vb = Kb + headsz;                              // 4 MB ([bh][32][S])
    unsigned long long* msk = (unsigned long long*)(Vb + 2 * headsz);  // 2 MB plain bitmask
    short* Wt = (short*)(msk + maskelems / 64);           // 192 KB
    float* pacc = (float*)(Wt + 3 * 128 * 256);
    size_t ns = 4;
    {
        const size_t fixed = (size_t)((char*)pacc - wsb);
        while (ns > 1 && fixed + ns * ((size_t)BATCH*NH*S_LEN*17*4) + 64 > ws_size)
            ns >>= 1;
    }
    float* pl = pacc + ns * (size_t)BATCH * NH * S_LEN * 16;
    int* flag = (int*)(pl + ns * (size_t)BATCH * NH * S_LEN);

    setup<<<dim3(1408), dim3(256), 0, stream>>>(
        (const unsigned int*)mask_raw, flag, Wq, Wk, Wv, Wt);
    phase1<<<dim3(768 + 512 + (unsigned)(maskelems / 4096)), dim3(256), 0, stream>>>(
        mask_raw, flag, msk, Xq, Xk, Xv, Wt, Qt, Kb, Vb);
    attn_mfma<<<dim3(S_LEN / 128, BATCH * NH, (unsigned)ns), dim3(256), 0, stream>>>(
        Qt, Kb, Vb, msk, pacc, pl);
    fc_ln<<<dim3(BATCH * S_LEN / 8), dim3(256), 0, stream>>>(pacc, pl, (int)ns, Wfc, gamma, beta, out);
}

// Round 13
// 73.880 us; speedup vs baseline: 3.8466x; 1.1052x over previous
//
#include <hip/hip_runtime.h>
#include <hip/hip_bf16.h>

#define S_LEN 2048
#define BATCH 4
#define NH 8
#define DK 16
#define DM 256
#define DP 128           // NH*DK
#define L2E 1.4426950408889634f
#define MAGIC_BOOL 0x600DB001

typedef short bf16x8 __attribute__((ext_vector_type(8)));
typedef short short4v __attribute__((ext_vector_type(4)));
typedef float f32x16 __attribute__((ext_vector_type(16)));

__device__ __forceinline__ short f2bf(float x) {
    __hip_bfloat16 h = __float2bfloat16(x);
    return __builtin_bit_cast(short, h);
}

union Frag { bf16x8 v; short4v h2[2]; };

// ---------------- Kernel A: setup = mask-dtype detect + W->frag-major bf16 -
// blocks [0,1024): detect (store MAGIC on bool evidence).
// blocks [1024,1072): cvt_w to fragment-major W2[inp][kb][hi][c][8]:
//   entry (inp,kb,hi,c) holds k = kb*16+4*hi+{0..3} and kb*16+8+4*hi+{0..3}
//   -> proj reads one contiguous 16B fragment per lane per kb (coalesced).
__global__ __launch_bounds__(256) void setup(
    const unsigned int* __restrict__ mrawu, int* __restrict__ flag,
    const float* __restrict__ Wq, const float* __restrict__ Wk,
    const float* __restrict__ Wv, short* __restrict__ Wt)
{
    const int bi = blockIdx.x;
    if (bi < 1024) {
        unsigned int u = mrawu[bi * 256 + threadIdx.x];   // first 1MB, in-bounds either dtype
        if (u & 0xFFFFFF00u) *flag = MAGIC_BOOL;          // benign same-value race
    } else {
        const int tid = (bi - 1024) * 256 + threadIdx.x;  // 12288 fragment entries
        const int c  = tid & 127;
        const int hi = (tid >> 7) & 1;
        const int kb = (tid >> 8) & 15;
        const int m  = tid >> 12;                         // 0=Q,1=K,2=V
        const float* W = (m == 0) ? Wq : (m == 1) ? Wk : Wv;
        const float scale = (m == 0) ? 0.25f * L2E : 1.0f;  // fold 1/sqrt(dk)*log2e into Wq
        const int k0 = kb * 16 + 4 * hi;
        union { bf16x8 v; short s[8]; } o;
        #pragma unroll
        for (int e = 0; e < 4; ++e) {
            o.s[e]     = f2bf(W[(size_t)(k0 + e) * DP + c] * scale);
            o.s[4 + e] = f2bf(W[(size_t)(k0 + 8 + e) * DP + c] * scale);
        }
        *(bf16x8*)(Wt + (size_t)tid * 8) = o.v;
    }
}

// ---------------- Kernel B: phase1 = proj_mfma U vinit U pack_mask ---------
// blocks [0,768): proj;  [768,1280): vinit;  [1280,5376): pack (plain bits)
__global__ __launch_bounds__(256) void phase1(
    const void* __restrict__ mraw, const int* __restrict__ flag,
    unsigned long long* __restrict__ ms64,
    const float* __restrict__ Xq, const float* __restrict__ Xk, const float* __restrict__ Xv,
    const short* __restrict__ Wt,
    short* __restrict__ Qt, short* __restrict__ Kb, short* __restrict__ Vb)
{
    __shared__ short xs_s[32 * 260];            // proj only; pitch 260 (2-way free)
    const int bi = blockIdx.x;
    const int t = threadIdx.x;

    if (bi < 768) {
        // ---------------- proj_mfma ----------------
        const int inp = bi >> 8;                // 0=Q,1=K,2=V
        const int s0 = (bi & 255) * 32;
        {
            // coalesced: each wave-load instruction covers one full 1KB X row
            const float* xbase = ((inp == 0) ? Xq : (inp == 1) ? Xk : Xv) + (size_t)s0 * 256;
            #pragma unroll
            for (int u = 0; u < 8; ++u) {
                const int idx = u * 1024 + t * 4;       // linear float index in 32x256 tile
                const int row = idx >> 8, col = idx & 255;
                float4 xv = *(const float4*)(xbase + idx);
                short4v o = { f2bf(xv.x), f2bf(xv.y), f2bf(xv.z), f2bf(xv.w) };
                *(short4v*)&xs_s[row * 260 + col] = o;
            }
        }
        __syncthreads();

        const int wave = t >> 6, lane = t & 63;
        const int lq = lane & 31, hi = lane >> 5;
        const int c = wave * 32 + lq;           // out col 0..127
        // fragment-major W2: one contiguous 16B fragment per kb, lanes consecutive in c
        const short* w2 = Wt + (((size_t)inp * 16 * 2 + hi) * 128 + c) * 8;

        f32x16 acc;
        #pragma unroll
        for (int i = 0; i < 16; ++i) acc[i] = 0.f;

        #pragma unroll
        for (int kb = 0; kb < 16; ++kb) {
            Frag af, bf_;
            af.h2[0] = *(const short4v*)&xs_s[lq * 260 + kb*16 + 4*hi];
            af.h2[1] = *(const short4v*)&xs_s[lq * 260 + kb*16 + 8 + 4*hi];
            bf_.v = *(const bf16x8*)(w2 + (size_t)kb * 2048);   // kb stride: 2*128*8 shorts
            acc = __builtin_amdgcn_mfma_f32_32x32x16_bf16(af.v, bf_.v, acc, 0, 0, 0);
        }

        // D: col(lane&31)=c, row(reg r)=s0 + (r&3)+8*(r>>2)+4*hi
        const int b = s0 >> 11, sl = s0 & (S_LEN - 1);
        const int h = c >> 4, d = c & 15;
        if (inp == 1) {
            // K: [bh][S][16] (attn stages K-tiles contiguously)
            #pragma unroll
            for (int r = 0; r < 16; ++r) {
                const int s = sl + (r & 3) + 8*(r >> 2) + 4*hi;
                Kb[(((size_t)(b * NH + h)) * S_LEN + s) * DK + d] = f2bf(acc[r]);
            }
        } else {
            // Q^T: [bh][16][S]; V^T: [bh][32][S] -- coalesced 8B stores
            short* base = (inp == 0)
                ? Qt + (((size_t)(b * NH + h)) * 16 + d) * S_LEN + sl
                : Vb + (((size_t)(b * NH + h)) * 32 + d) * S_LEN + sl;
            #pragma unroll
            for (int g = 0; g < 4; ++g) {
                short4v vv = { f2bf(acc[4*g]), f2bf(acc[4*g+1]), f2bf(acc[4*g+2]), f2bf(acc[4*g+3]) };
                *(short4v*)(base + 8*g + 4*hi) = vv;
            }
        }
    } else if (bi < 1280) {
        // ---------------- vinit ----------------
        const int tid = (bi - 768) * 256 + t;   // 131072 total
        const int bh = tid >> 12;
        const int rem = tid & 4095;
        const int row = 16 + (rem >> 11) * 4;   // 16 or 20
        const int s = rem & 2047;
        Vb[((size_t)bh * 32 + row) * S_LEN + s] = (short)0x3F80;  // bf16 1.0
    } else {
        // ---------------- pack_mask: plain ballot bits, tile-major ----------
        // u64 at [tile][row][w0h]; bit j = mask[row][tile*128 + 64*w0h + j]
        const int lane = t & 63;
        const size_t kbase = ((size_t)(bi - 1280) * 4 + (t >> 6)) * 1024;  // 16 groups/wave
        const int isInt = (*flag != MAGIC_BOOL);

        int v[16];
        if (isInt) {
            const int* p = (const int*)mraw + kbase + lane;
            #pragma unroll
            for (int g = 0; g < 16; ++g) v[g] = p[g * 64];
        } else {
            const unsigned char* p = (const unsigned char*)mraw + kbase + lane;
            #pragma unroll
            for (int g = 0; g < 16; ++g) v[g] = p[g * 64];
        }

        const size_t row = kbase >> 11;         // b*S + q
        const int koff0 = (int)(kbase & 2047);

        #pragma unroll
        for (int g = 0; g < 16; ++g) {
            const unsigned long long W = __ballot(v[g] != 0);
            if (lane == 0) {
                const int koff = koff0 + g * 64;
                ms64[(size_t)(koff >> 7) * (BATCH*S_LEN*2) + row*2 + ((koff >> 6) & 1)] = W;
            }
        }
    }
}

// ---------------- Kernel C: MFMA flash attention, LDS-staged K/V -----------
// grid (S/128, B*H, ns); block 256 = 4 waves x 32 q-rows.
__global__ __launch_bounds__(256, 8) void attn_mfma(
    const short* __restrict__ Qt, const short* __restrict__ Kb, const short* __restrict__ Vb,
    const unsigned long long* __restrict__ ms64, float* __restrict__ pacc, float* __restrict__ pl)
{
    __shared__ short kt_s[128 * 20];   // K tile: pitch 20 shorts (10 dw)
    __shared__ short vt_s[32 * 132];   // V^T tile: pitch 132 shorts (66 dw)

    const int bh = blockIdx.y;
    const int b = bh >> 3;
    const int z = blockIdx.z;
    const int t = threadIdx.x;
    const int wave = t >> 6, lane = t & 63;
    const int lq = lane & 31, hi = lane >> 5;
    const int qrow = blockIdx.x * 128 + wave * 32 + lq;

    Frag qf;
    {
        // Q^T [bh][16][S]: 8 scalar reads, coalesced across lanes (qrow = ..+lq)
        const short* qt = Qt + (size_t)bh * 16 * S_LEN + qrow;
        #pragma unroll
        for (int j = 0; j < 4; ++j) {
            qf.h2[0][j] = qt[(size_t)(4*hi + j) * S_LEN];
            qf.h2[1][j] = qt[(size_t)(8 + 4*hi + j) * S_LEN];
        }
    }

    f32x16 acc;
    #pragma unroll
    for (int i = 0; i < 16; ++i) acc[i] = 0.f;

    const short* kbase = Kb + (size_t)bh * S_LEN * DK;
    const short* vbase = Vb + (size_t)bh * 32 * S_LEN;
    const unsigned long long* mbase = ms64 + ((size_t)b * S_LEN + qrow) * 2;

    const int tiles = (S_LEN / 128) / gridDim.z;
    const int t0 = z * tiles, t1 = t0 + tiles;

    for (int tile = t0; tile < t1; ++tile) {
        const int k0 = tile * 128;

        // ---- stage K tile (4KB, contiguous) and V^T tile (8KB, 256B rows)
        {
            const uint4 kv = *(const uint4*)(kbase + (size_t)k0 * DK + t * 8);
            short* kdst = &kt_s[(t >> 1) * 20 + (t & 1) * 8];
            *(uint2*)(kdst)     = *(uint2*)&kv;
            *(uint2*)(kdst + 4) = *((uint2*)&kv + 1);

            const short* vsrc = vbase + (size_t)(t >> 3) * S_LEN + k0 + (t & 7) * 16;
            uint4 v0 = *(const uint4*)(vsrc);
            uint4 v1 = *(const uint4*)(vsrc + 8);
            short* vdst = &vt_s[(t >> 3) * 132 + (t & 7) * 16];
            *(uint2*)(vdst)      = *(uint2*)&v0;
            *(uint2*)(vdst + 4)  = *((uint2*)&v0 + 1);
            *(uint2*)(vdst + 8)  = *(uint2*)&v1;
            *(uint2*)(vdst + 12) = *((uint2*)&v1 + 1);
        }
        __syncthreads();

        // two plain-bit u64 words cover this 128-key tile
        const unsigned long long* mw = mbase + (size_t)tile * (BATCH * S_LEN * 2);
        const unsigned long long W64a = mw[0], W64b = mw[1];

        #pragma unroll
        for (int kt = 0; kt < 4; ++kt) {
            // mask bits: key(r) = 32*(kt&1) + 4*hi + (r&3)+8*(r>>2) within word kt>>1
            const unsigned int W = (unsigned int)(((kt < 2) ? W64a : W64b)
                                                  >> (32*(kt & 1) + 4*hi));
            f32x16 ci;
            #pragma unroll
            for (int r = 0; r < 16; ++r) {
                const int bit = (r & 3) + 8*(r >> 2);
                ci[r] = __int_as_float(((int)(W << (31 - bit)) >> 31) & 0xC2C80000);
            }

            // QK^T for 32 keys (log2-domain scores via scaled Wq)
            Frag kf;
            kf.h2[0] = *(const short4v*)&kt_s[(kt*32 + lq) * 20 + 4*hi];
            kf.h2[1] = *(const short4v*)&kt_s[(kt*32 + lq) * 20 + 8 + 4*hi];
            f32x16 p = __builtin_amdgcn_mfma_f32_32x32x16_bf16(kf.v, qf.v, ci, 0, 0, 0);

            #pragma unroll
            for (int r = 0; r < 16; ++r) p[r] = __builtin_amdgcn_exp2f(p[r]);

            // PV: 2 MFMAs of 16 keys; packed bf16 convert (1 instr / 2 vals)
            #pragma unroll
            for (int j = 0; j < 2; ++j) {
                union { bf16x8 v; unsigned int u[4]; } pf;
                #pragma unroll
                for (int e = 0; e < 4; ++e) {
                    asm("v_cvt_pk_bf16_f32 %0, %1, %2"
                        : "=v"(pf.u[e]) : "v"(p[j*8 + 2*e]), "v"(p[j*8 + 2*e + 1]));
                }
                Frag vf;
                const int vo = lq * 132 + (kt*2 + j) * 16 + 4*hi;
                vf.h2[0] = *(const short4v*)&vt_s[vo];
                vf.h2[1] = *(const short4v*)&vt_s[vo + 8];
                acc = __builtin_amdgcn_mfma_f32_32x32x16_bf16(vf.v, pf.v, acc, 0, 0, 0);
            }
        }
        __syncthreads();   // protect LDS before next tile's stage
    }

    // partial store (unnormalized); acc[8] = sum of P (ones-row of V)
    float* pb = pacc + (((size_t)z * (BATCH*NH) + bh) * S_LEN + qrow) * 16;
    float4 o1 = { acc[0], acc[1], acc[2], acc[3] };
    float4 o2 = { acc[4], acc[5], acc[6], acc[7] };
    *(float4*)(pb + 4*hi) = o1;
    *(float4*)(pb + 8 + 4*hi) = o2;
    if (hi == 0) pl[((size_t)z * (BATCH*NH) + bh) * S_LEN + qrow] = acc[8];
}

// ---------------- Kernel D: combine + FC (ctx @ Wfc) + LayerNorm -----------
__global__ __launch_bounds__(256) void fc_ln(
    const float* __restrict__ pacc, const float* __restrict__ pl, int ns,
    const float* __restrict__ Wfc,
    const float* __restrict__ gamma, const float* __restrict__ beta,
    float* __restrict__ out)
{
    __shared__ float cs[8][DP];
    __shared__ float ys[8][256];
    __shared__ float red[16];
    const int t = threadIdx.x;
    const int row0 = blockIdx.x * 8;

    {
        const int idx = t * 4;
        const int r = idx >> 7, k = idx & 127;       // r 0..7, k mult of 4
        const int grow = row0 + r;
        const int b = grow >> 11, q = grow & (S_LEN - 1);
        const int h = k >> 4, d0 = k & 15;           // d0 in {0,4,8,12}
        float4 s = {0.f, 0.f, 0.f, 0.f};
        float L = 0.f;
        for (int z = 0; z < ns; ++z) {
            const size_t o = ((size_t)z * (BATCH*NH) + b * NH + h) * S_LEN + q;
            const float4 a = *(const float4*)(pacc + o * 16 + d0);
            s.x += a.x; s.y += a.y; s.z += a.z; s.w += a.w;
            L += pl[o];
        }
        const float inv = 1.0f / L;
        float4 o4 = { s.x * inv, s.y * inv, s.z * inv, s.w * inv };
        *(float4*)&cs[r][k] = o4;
    }
    __syncthreads();

    float acc[8] = {0,0,0,0,0,0,0,0};
    for (int k = 0; k < DP; k += 4) {
        const float w0 = Wfc[(k+0)*DM + t];
        const float w1 = Wfc[(k+1)*DM + t];
        const float w2 = Wfc[(k+2)*DM + t];
        const float w3 = Wfc[(k+3)*DM + t];
        #pragma unroll
        for (int r = 0; r < 8; ++r) {
            float4 x = *(const float4*)&cs[r][k];
            acc[r] = fmaf(x.x, w0, fmaf(x.y, w1, fmaf(x.z, w2, fmaf(x.w, w3, acc[r]))));
        }
    }

    #pragma unroll
    for (int r = 0; r < 8; ++r) ys[r][t] = acc[r];
    __syncthreads();

    const int w = t >> 6, lj = t & 63;
    #pragma unroll
    for (int rr = 0; rr < 2; ++rr) {
        const int r = w * 2 + rr;
        float a0 = ys[r][lj], a1 = ys[r][lj+64], a2 = ys[r][lj+128], a3 = ys[r][lj+192];
        float s1 = a0 + a1 + a2 + a3;
        float s2 = a0*a0 + a1*a1 + a2*a2 + a3*a3;
        #pragma unroll
        for (int off = 32; off; off >>= 1) {
            s1 += __shfl_xor(s1, off);
            s2 += __shfl_xor(s2, off);
        }
        if (lj == 0) {
            float mu = s1 * (1.0f/256.0f);
            float var = s2 * (1.0f/256.0f) - mu*mu;
            red[r*2]     = mu;
            red[r*2 + 1] = rsqrtf(var + 1e-5f);
        }
    }
    __syncthreads();

    const float g = gamma[t], be = beta[t];
    #pragma unroll
    for (int r = 0; r < 8; ++r) {
        float y = (acc[r] - red[r*2]) * red[r*2 + 1];
        out[(size_t)(row0 + r) * DM + t] = fmaf(y, g, be);
    }
}

extern "C" void kernel_launch(void* const* d_in, const int* in_sizes, int n_in,
                              void* d_out, int out_size, void* d_ws, size_t ws_size,
                              hipStream_t stream)
{
    const float* Xq = (const float*)d_in[0];
    const float* Xk = (const float*)d_in[1];
    const float* Xv = (const float*)d_in[2];
    const void* mask_raw = d_in[3];
    const float* Wq  = (const float*)d_in[4];
    const float* Wk  = (const float*)d_in[5];
    const float* Wv  = (const float*)d_in[6];
    const float* Wfc = (const float*)d_in[7];
    const float* gamma = (const float*)d_in[8];
    const float* beta  = (const float*)d_in[9];
    float* out = (float*)d_out;

    const size_t headsz = (size_t)BATCH * NH * S_LEN * DK;      // 1,048,576 elems
    const size_t maskelems = (size_t)BATCH * S_LEN * S_LEN;     // 16.8M

    char* wsb = (char*)d_ws;
    short* Qt = (short*)wsb;                              // 2 MB ([bh][16][S] transposed)
    short* Kb = Qt + headsz;                              // 2 MB ([bh][S][16])
    short* Vb = Kb + headsz;                              // 4 MB ([bh][32][S])
    unsigned long long* msk = (unsigned long long*)(Vb + 2 * headsz);  // 2 MB plain bitmask
    short* Wt = (short*)(msk + maskelems / 64);           // 192 KB fragment-major
    float* pacc = (float*)(Wt + 3 * 128 * 256);
    size_t ns = 4;
    {
        const size_t fixed = (size_t)((char*)pacc - wsb);
        while (ns > 1 && fixed + ns * ((size_t)BATCH*NH*S_LEN*17*4) + 64 > ws_size)
            ns >>= 1;
    }
    float* pl = pacc + ns * (size_t)BATCH * NH * S_LEN * 16;
    int* flag = (int*)(pl + ns * (size_t)BATCH * NH * S_LEN);

    setup<<<dim3(1072), dim3(256), 0, stream>>>(
        (const unsigned int*)mask_raw, flag, Wq, Wk, Wv, Wt);
    phase1<<<dim3(768 + 512 + (unsigned)(maskelems / 4096)), dim3(256), 0, stream>>>(
        mask_raw, flag, msk, Xq, Xk, Xv, Wt, Qt, Kb, Vb);
    attn_mfma<<<dim3(S_LEN / 128, BATCH * NH, (unsigned)ns), dim3(256), 0, stream>>>(
        Qt, Kb, Vb, msk, pacc, pl);
    fc_ln<<<dim3(BATCH * S_LEN / 8), dim3(256), 0, stream>>>(pacc, pl, (int)ns, Wfc, gamma, beta, out);
}

// Round 14
// 72.441 us; speedup vs baseline: 3.9231x; 1.0199x over previous
//
#include <hip/hip_runtime.h>
#include <hip/hip_bf16.h>

#define S_LEN 2048
#define BATCH 4
#define NH 8
#define DK 16
#define DM 256
#define DP 128           // NH*DK
#define L2E 1.4426950408889634f

typedef short bf16x8 __attribute__((ext_vector_type(8)));
typedef short short4v __attribute__((ext_vector_type(4)));
typedef float f32x16 __attribute__((ext_vector_type(16)));

__device__ __forceinline__ short f2bf(float x) {
    __hip_bfloat16 h = __float2bfloat16(x);
    return __builtin_bit_cast(short, h);
}

union Frag { bf16x8 v; short4v h2[2]; };

// ---------------- Kernel A: phase1 = proj_mfma U vinit U pack_mask ---------
// blocks [0,768): proj (W converted in-register from f32, coalesced L2 reads)
// blocks [768,1280): vinit;  [1280,5376): pack (per-block dtype detect)
__global__ __launch_bounds__(256) void phase1(
    const void* __restrict__ mraw,
    unsigned long long* __restrict__ ms64,
    const float* __restrict__ Xq, const float* __restrict__ Xk, const float* __restrict__ Xv,
    const float* __restrict__ Wq, const float* __restrict__ Wk, const float* __restrict__ Wv,
    short* __restrict__ Qt, short* __restrict__ Kb, short* __restrict__ Vb)
{
    __shared__ short xs_s[32 * 260];            // proj only; pitch 260 (2-way free)
    __shared__ int isBool;                      // pack only
    const int bi = blockIdx.x;
    const int t = threadIdx.x;

    if (bi < 768) {
        // ---------------- proj_mfma ----------------
        const int inp = bi >> 8;                // 0=Q,1=K,2=V
        const int s0 = (bi & 255) * 32;
        {
            // coalesced: each wave-load instruction covers one full 1KB X row
            const float* xbase = ((inp == 0) ? Xq : (inp == 1) ? Xk : Xv) + (size_t)s0 * 256;
            #pragma unroll
            for (int u = 0; u < 8; ++u) {
                const int idx = u * 1024 + t * 4;       // linear float index in 32x256 tile
                const int row = idx >> 8, col = idx & 255;
                float4 xv = *(const float4*)(xbase + idx);
                short4v o = { f2bf(xv.x), f2bf(xv.y), f2bf(xv.z), f2bf(xv.w) };
                *(short4v*)&xs_s[row * 260 + col] = o;
            }
        }
        __syncthreads();

        const int wave = t >> 6, lane = t & 63;
        const int lq = lane & 31, hi = lane >> 5;
        const int c = wave * 32 + lq;           // out col 0..127

        // per-lane W fragments straight from f32 (lane-consecutive in c => coalesced; L2-hot)
        const float* W = (inp == 0) ? Wq : (inp == 1) ? Wk : Wv;
        const float scale = (inp == 0) ? 0.25f * L2E : 1.0f;   // fold 1/sqrt(dk)*log2e into Wq
        Frag wf[16];
        #pragma unroll
        for (int kb = 0; kb < 16; ++kb) {
            const int k0 = kb * 16 + 4 * hi;
            union { bf16x8 v; short s[8]; } o;
            #pragma unroll
            for (int e = 0; e < 4; ++e) {
                o.s[e]     = f2bf(W[(size_t)(k0 + e) * DP + c] * scale);
                o.s[4 + e] = f2bf(W[(size_t)(k0 + 8 + e) * DP + c] * scale);
            }
            wf[kb].v = o.v;
        }

        f32x16 acc;
        #pragma unroll
        for (int i = 0; i < 16; ++i) acc[i] = 0.f;

        #pragma unroll
        for (int kb = 0; kb < 16; ++kb) {
            Frag af;
            af.h2[0] = *(const short4v*)&xs_s[lq * 260 + kb*16 + 4*hi];
            af.h2[1] = *(const short4v*)&xs_s[lq * 260 + kb*16 + 8 + 4*hi];
            acc = __builtin_amdgcn_mfma_f32_32x32x16_bf16(af.v, wf[kb].v, acc, 0, 0, 0);
        }

        // D: col(lane&31)=c, row(reg r)=s0 + (r&3)+8*(r>>2)+4*hi
        const int b = s0 >> 11, sl = s0 & (S_LEN - 1);
        const int h = c >> 4, d = c & 15;
        if (inp == 1) {
            // K: [bh][S][16] (attn stages K-tiles contiguously)
            #pragma unroll
            for (int r = 0; r < 16; ++r) {
                const int s = sl + (r & 3) + 8*(r >> 2) + 4*hi;
                Kb[(((size_t)(b * NH + h)) * S_LEN + s) * DK + d] = f2bf(acc[r]);
            }
        } else {
            // Q^T: [bh][16][S]; V^T: [bh][32][S] -- coalesced 8B stores
            short* base = (inp == 0)
                ? Qt + (((size_t)(b * NH + h)) * 16 + d) * S_LEN + sl
                : Vb + (((size_t)(b * NH + h)) * 32 + d) * S_LEN + sl;
            #pragma unroll
            for (int g = 0; g < 4; ++g) {
                short4v vv = { f2bf(acc[4*g]), f2bf(acc[4*g+1]), f2bf(acc[4*g+2]), f2bf(acc[4*g+3]) };
                *(short4v*)(base + 8*g + 4*hi) = vv;
            }
        }
    } else if (bi < 1280) {
        // ---------------- vinit ----------------
        const int tid = (bi - 768) * 256 + t;   // 131072 total
        const int bh = tid >> 12;
        const int rem = tid & 4095;
        const int row = 16 + (rem >> 11) * 4;   // 16 or 20
        const int s = rem & 2047;
        Vb[((size_t)bh * 32 + row) * S_LEN + s] = (short)0x3F80;  // bf16 1.0
    } else {
        // ---------------- pack_mask: per-block dtype detect + plain bits ----
        const size_t kbase0 = (size_t)(bi - 1280) * 4096;   // block's element range
        // detect on own range: u32 view of the bool-byte span [kbase0, kbase0+4096)
        // bool 0/1 bytes -> high bytes hit with p=7/8 per word (2^-768 miss over 256);
        // int32 0/1 values -> high bytes always 0. In-bounds for both dtypes.
        if (t == 0) isBool = 0;
        __syncthreads();
        {
            unsigned int u = ((const unsigned int*)mraw)[(kbase0 >> 2) + t * 4];
            if (u & 0xFFFFFF00u) isBool = 1;    // benign same-value race
        }
        __syncthreads();

        const int lane = t & 63;
        const size_t kbase = kbase0 + (size_t)(t >> 6) * 1024;   // 16 groups/wave
        int v[16];
        if (!isBool) {
            const int* p = (const int*)mraw + kbase + lane;
            #pragma unroll
            for (int g = 0; g < 16; ++g) v[g] = p[g * 64];
        } else {
            const unsigned char* p = (const unsigned char*)mraw + kbase + lane;
            #pragma unroll
            for (int g = 0; g < 16; ++g) v[g] = p[g * 64];
        }

        const size_t row = kbase >> 11;         // b*S + q
        const int koff0 = (int)(kbase & 2047);

        // u64 at [tile][row][w0h]; bit j = mask[row][tile*128 + 64*w0h + j]
        #pragma unroll
        for (int g = 0; g < 16; ++g) {
            const unsigned long long W = __ballot(v[g] != 0);
            if (lane == 0) {
                const int koff = koff0 + g * 64;
                ms64[(size_t)(koff >> 7) * (BATCH*S_LEN*2) + row*2 + ((koff >> 6) & 1)] = W;
            }
        }
    }
}

// ---------------- Kernel B: MFMA flash attention, LDS-staged K/V -----------
// grid (S/128, B*H, ns); block 256 = 4 waves x 32 q-rows.
__global__ __launch_bounds__(256, 8) void attn_mfma(
    const short* __restrict__ Qt, const short* __restrict__ Kb, const short* __restrict__ Vb,
    const unsigned long long* __restrict__ ms64, float* __restrict__ pacc, float* __restrict__ pl)
{
    __shared__ short kt_s[128 * 20];   // K tile: pitch 20 shorts (10 dw)
    __shared__ short vt_s[32 * 132];   // V^T tile: pitch 132 shorts (66 dw)

    const int bh = blockIdx.y;
    const int b = bh >> 3;
    const int z = blockIdx.z;
    const int t = threadIdx.x;
    const int wave = t >> 6, lane = t & 63;
    const int lq = lane & 31, hi = lane >> 5;
    const int qrow = blockIdx.x * 128 + wave * 32 + lq;

    Frag qf;
    {
        // Q^T [bh][16][S]: 8 scalar reads, coalesced across lanes (qrow = ..+lq)
        const short* qt = Qt + (size_t)bh * 16 * S_LEN + qrow;
        #pragma unroll
        for (int j = 0; j < 4; ++j) {
            qf.h2[0][j] = qt[(size_t)(4*hi + j) * S_LEN];
            qf.h2[1][j] = qt[(size_t)(8 + 4*hi + j) * S_LEN];
        }
    }

    f32x16 acc;
    #pragma unroll
    for (int i = 0; i < 16; ++i) acc[i] = 0.f;

    const short* kbase = Kb + (size_t)bh * S_LEN * DK;
    const short* vbase = Vb + (size_t)bh * 32 * S_LEN;
    const unsigned long long* mbase = ms64 + ((size_t)b * S_LEN + qrow) * 2;

    const int tiles = (S_LEN / 128) / gridDim.z;
    const int t0 = z * tiles, t1 = t0 + tiles;

    for (int tile = t0; tile < t1; ++tile) {
        const int k0 = tile * 128;

        // ---- stage K tile (4KB, contiguous) and V^T tile (8KB, 256B rows)
        {
            const uint4 kv = *(const uint4*)(kbase + (size_t)k0 * DK + t * 8);
            short* kdst = &kt_s[(t >> 1) * 20 + (t & 1) * 8];
            *(uint2*)(kdst)     = *(uint2*)&kv;
            *(uint2*)(kdst + 4) = *((uint2*)&kv + 1);

            const short* vsrc = vbase + (size_t)(t >> 3) * S_LEN + k0 + (t & 7) * 16;
            uint4 v0 = *(const uint4*)(vsrc);
            uint4 v1 = *(const uint4*)(vsrc + 8);
            short* vdst = &vt_s[(t >> 3) * 132 + (t & 7) * 16];
            *(uint2*)(vdst)      = *(uint2*)&v0;
            *(uint2*)(vdst + 4)  = *((uint2*)&v0 + 1);
            *(uint2*)(vdst + 8)  = *(uint2*)&v1;
            *(uint2*)(vdst + 12) = *((uint2*)&v1 + 1);
        }
        __syncthreads();

        // two plain-bit u64 words cover this 128-key tile
        const unsigned long long* mw = mbase + (size_t)tile * (BATCH * S_LEN * 2);
        const unsigned long long W64a = mw[0], W64b = mw[1];

        #pragma unroll
        for (int kt = 0; kt < 4; ++kt) {
            // mask bits: key(r) = 32*(kt&1) + 4*hi + (r&3)+8*(r>>2) within word kt>>1
            const unsigned int W = (unsigned int)(((kt < 2) ? W64a : W64b)
                                                  >> (32*(kt & 1) + 4*hi));
            f32x16 ci;
            #pragma unroll
            for (int r = 0; r < 16; ++r) {
                const int bit = (r & 3) + 8*(r >> 2);
                ci[r] = __int_as_float(((int)(W << (31 - bit)) >> 31) & 0xC2C80000);
            }

            // QK^T for 32 keys (log2-domain scores via scaled Wq)
            Frag kf;
            kf.h2[0] = *(const short4v*)&kt_s[(kt*32 + lq) * 20 + 4*hi];
            kf.h2[1] = *(const short4v*)&kt_s[(kt*32 + lq) * 20 + 8 + 4*hi];
            f32x16 p = __builtin_amdgcn_mfma_f32_32x32x16_bf16(kf.v, qf.v, ci, 0, 0, 0);

            #pragma unroll
            for (int r = 0; r < 16; ++r) p[r] = __builtin_amdgcn_exp2f(p[r]);

            // PV: 2 MFMAs of 16 keys; packed bf16 convert (1 instr / 2 vals)
            #pragma unroll
            for (int j = 0; j < 2; ++j) {
                union { bf16x8 v; unsigned int u[4]; } pf;
                #pragma unroll
                for (int e = 0; e < 4; ++e) {
                    asm("v_cvt_pk_bf16_f32 %0, %1, %2"
                        : "=v"(pf.u[e]) : "v"(p[j*8 + 2*e]), "v"(p[j*8 + 2*e + 1]));
                }
                Frag vf;
                const int vo = lq * 132 + (kt*2 + j) * 16 + 4*hi;
                vf.h2[0] = *(const short4v*)&vt_s[vo];
                vf.h2[1] = *(const short4v*)&vt_s[vo + 8];
                acc = __builtin_amdgcn_mfma_f32_32x32x16_bf16(vf.v, pf.v, acc, 0, 0, 0);
            }
        }
        __syncthreads();   // protect LDS before next tile's stage
    }

    // partial store (unnormalized); acc[8] = sum of P (ones-row of V)
    float* pb = pacc + (((size_t)z * (BATCH*NH) + bh) * S_LEN + qrow) * 16;
    float4 o1 = { acc[0], acc[1], acc[2], acc[3] };
    float4 o2 = { acc[4], acc[5], acc[6], acc[7] };
    *(float4*)(pb + 4*hi) = o1;
    *(float4*)(pb + 8 + 4*hi) = o2;
    if (hi == 0) pl[((size_t)z * (BATCH*NH) + bh) * S_LEN + qrow] = acc[8];
}

// ---------------- Kernel C: combine + FC (ctx @ Wfc) + LayerNorm -----------
__global__ __launch_bounds__(256) void fc_ln(
    const float* __restrict__ pacc, const float* __restrict__ pl, int ns,
    const float* __restrict__ Wfc,
    const float* __restrict__ gamma, const float* __restrict__ beta,
    float* __restrict__ out)
{
    __shared__ float cs[8][DP];
    __shared__ float ys[8][256];
    __shared__ float red[16];
    const int t = threadIdx.x;
    const int row0 = blockIdx.x * 8;

    {
        const int idx = t * 4;
        const int r = idx >> 7, k = idx & 127;       // r 0..7, k mult of 4
        const int grow = row0 + r;
        const int b = grow >> 11, q = grow & (S_LEN - 1);
        const int h = k >> 4, d0 = k & 15;           // d0 in {0,4,8,12}
        float4 s = {0.f, 0.f, 0.f, 0.f};
        float L = 0.f;
        for (int z = 0; z < ns; ++z) {
            const size_t o = ((size_t)z * (BATCH*NH) + b * NH + h) * S_LEN + q;
            const float4 a = *(const float4*)(pacc + o * 16 + d0);
            s.x += a.x; s.y += a.y; s.z += a.z; s.w += a.w;
            L += pl[o];
        }
        const float inv = 1.0f / L;
        float4 o4 = { s.x * inv, s.y * inv, s.z * inv, s.w * inv };
        *(float4*)&cs[r][k] = o4;
    }
    __syncthreads();

    float acc[8] = {0,0,0,0,0,0,0,0};
    for (int k = 0; k < DP; k += 4) {
        const float w0 = Wfc[(k+0)*DM + t];
        const float w1 = Wfc[(k+1)*DM + t];
        const float w2 = Wfc[(k+2)*DM + t];
        const float w3 = Wfc[(k+3)*DM + t];
        #pragma unroll
        for (int r = 0; r < 8; ++r) {
            float4 x = *(const float4*)&cs[r][k];
            acc[r] = fmaf(x.x, w0, fmaf(x.y, w1, fmaf(x.z, w2, fmaf(x.w, w3, acc[r]))));
        }
    }

    #pragma unroll
    for (int r = 0; r < 8; ++r) ys[r][t] = acc[r];
    __syncthreads();

    const int w = t >> 6, lj = t & 63;
    #pragma unroll
    for (int rr = 0; rr < 2; ++rr) {
        const int r = w * 2 + rr;
        float a0 = ys[r][lj], a1 = ys[r][lj+64], a2 = ys[r][lj+128], a3 = ys[r][lj+192];
        float s1 = a0 + a1 + a2 + a3;
        float s2 = a0*a0 + a1*a1 + a2*a2 + a3*a3;
        #pragma unroll
        for (int off = 32; off; off >>= 1) {
            s1 += __shfl_xor(s1, off);
            s2 += __shfl_xor(s2, off);
        }
        if (lj == 0) {
            float mu = s1 * (1.0f/256.0f);
            float var = s2 * (1.0f/256.0f) - mu*mu;
            red[r*2]     = mu;
            red[r*2 + 1] = rsqrtf(var + 1e-5f);
        }
    }
    __syncthreads();

    const float g = gamma[t], be = beta[t];
    #pragma unroll
    for (int r = 0; r < 8; ++r) {
        float y = (acc[r] - red[r*2]) * red[r*2 + 1];
        out[(size_t)(row0 + r) * DM + t] = fmaf(y, g, be);
    }
}

extern "C" void kernel_launch(void* const* d_in, const int* in_sizes, int n_in,
                              void* d_out, int out_size, void* d_ws, size_t ws_size,
                              hipStream_t stream)
{
    const float* Xq = (const float*)d_in[0];
    const float* Xk = (const float*)d_in[1];
    const float* Xv = (const float*)d_in[2];
    const void* mask_raw = d_in[3];
    const float* Wq  = (const float*)d_in[4];
    const float* Wk  = (const float*)d_in[5];
    const float* Wv  = (const float*)d_in[6];
    const float* Wfc = (const float*)d_in[7];
    const float* gamma = (const float*)d_in[8];
    const float* beta  = (const float*)d_in[9];
    float* out = (float*)d_out;

    const size_t headsz = (size_t)BATCH * NH * S_LEN * DK;      // 1,048,576 elems
    const size_t maskelems = (size_t)BATCH * S_LEN * S_LEN;     // 16.8M

    char* wsb = (char*)d_ws;
    short* Qt = (short*)wsb;                              // 2 MB ([bh][16][S] transposed)
    short* Kb = Qt + headsz;                              // 2 MB ([bh][S][16])
    short* Vb = Kb + headsz;                              // 4 MB ([bh][32][S])
    unsigned long long* msk = (unsigned long long*)(Vb + 2 * headsz);  // 2 MB plain bitmask
    float* pacc = (float*)(msk + maskelems / 64);
    size_t ns = 4;
    {
        const size_t fixed = (size_t)((char*)pacc - wsb);
        while (ns > 1 && fixed + ns * ((size_t)BATCH*NH*S_LEN*17*4) > ws_size)
            ns >>= 1;
    }
    float* pl = pacc + ns * (size_t)BATCH * NH * S_LEN * 16;

    phase1<<<dim3(768 + 512 + (unsigned)(maskelems / 4096)), dim3(256), 0, stream>>>(
        mask_raw, msk, Xq, Xk, Xv, Wq, Wk, Wv, Qt, Kb, Vb);
    attn_mfma<<<dim3(S_LEN / 128, BATCH * NH, (unsigned)ns), dim3(256), 0, stream>>>(
        Qt, Kb, Vb, msk, pacc, pl);
    fc_ln<<<dim3(BATCH * S_LEN / 8), dim3(256), 0, stream>>>(pacc, pl, (int)ns, Wfc, gamma, beta, out);
}